// Round 4
// baseline (2315.483 us; speedup 1.0000x reference)
//
#include <hip/hip_runtime.h>
#include <hip/hip_bf16.h>
#include <math.h>

// Problem constants
#define NB   256      // batch
#define ML   31       // MAX_LEN
#define NT   30       // T = MAX_LEN-1 decode steps
#define NV   10000    // vocab
#define NH   512      // hidden
#define NE   512      // embed
#define NG   2048     // 4*H gates

// Output layout (floats): preds (256,31,10000) | target (256,30) | dec_len (256,)
#define OFF_TGT  (256LL*31LL*10000LL)
#define OFF_DEC  (OFF_TGT + 256LL*30LL)
#define PRED_B   (31LL*10000LL)

typedef __attribute__((ext_vector_type(8))) short bf16x8;
typedef __attribute__((ext_vector_type(4))) float f32x4;

__device__ inline unsigned short f2bf(float f) {
    unsigned int x = __float_as_uint(f);
    unsigned int r = x + 0x7FFFu + ((x >> 16) & 1u);   // RNE
    return (unsigned short)(r >> 16);
}
__device__ inline float bf2f(unsigned short u) {
    return __uint_as_float((unsigned int)u << 16);
}

// ---------- sort: stable descending argsort + per-step active counts ----------
__global__ void sort_k(const int* __restrict__ lens, int* __restrict__ order,
                       int* __restrict__ cnt, int* __restrict__ start,
                       float* __restrict__ out_dec) {
    __shared__ int sd[NB];
    int i = threadIdx.x;
    int li = lens[i];
    int r = 0;
    for (int j = 0; j < NB; j++) {
        int lj = lens[j];
        r += (lj > li) || (lj == li && j < i);
    }
    order[r] = i;
    out_dec[r] = (float)(li - 1);
    sd[r] = li - 1;
    __syncthreads();
    if (i < NT) {
        int c = 0;
        for (int b = 0; b < NB; b++) c += (sd[b] > i);
        cnt[i] = c;
    }
    __syncthreads();
    if (i == 0) {
        int s = 0;
        for (int t = 0; t < NT; t++) { start[t] = s; s += cnt[t]; }
        start[NT] = s;                 // n_active
    }
}

// ---------- gather sorted rows (bf16 image), emit target ----------------------
__global__ void gather_k(const float* __restrict__ gimg, const int* __restrict__ w_in,
                         const int* __restrict__ order,
                         unsigned short* __restrict__ g_sb, int* __restrict__ wsort,
                         float* __restrict__ out_tgt) {
    int r = blockIdx.x, tid = threadIdx.x;
    int o = order[r];
    for (int e = tid; e < NE; e += 256)
        g_sb[r * NE + e] = f2bf(gimg[o * NE + e]);
    if (tid < ML) wsort[r * ML + tid] = w_in[o * ML + tid];
    if (tid < NT) out_tgt[r * NT + tid] = (float)w_in[o * ML + tid + 1];
}

// ---------- compact active-row lists ------------------------------------------
__global__ void rowlist_k(const int* __restrict__ wsort, const int* __restrict__ cnt,
                          const int* __restrict__ start,
                          int* __restrict__ rowlist, int* __restrict__ rowwc) {
    int t = blockIdx.x, b = threadIdx.x;
    if (b < cnt[t]) {
        int pos = start[t] + b;
        rowlist[pos] = t * 256 + b;
        rowwc[pos] = wsort[b * ML + t];
    }
}

// ---------- fp32 -> bf16 conversions ------------------------------------------
__global__ void f2b_k(const float* __restrict__ src, unsigned short* __restrict__ dst, int n4) {
    int i = blockIdx.x * 256 + threadIdx.x;
    if (i >= n4) return;
    float4 v = ((const float4*)src)[i];
    ushort4 o;
    o.x = f2bf(v.x); o.y = f2bf(v.y); o.z = f2bf(v.z); o.w = f2bf(v.w);
    ((ushort4*)dst)[i] = o;
}

// dst[j][k] = bf16(W_ih[j][koff+k]), j<2048, k<512
__global__ void wih_k(const float* __restrict__ W_ih, unsigned short* __restrict__ dst, int koff) {
    int gid = blockIdx.x * 256 + threadIdx.x;   // 2048*128 float4 chunks
    int j = gid >> 7, k4 = gid & 127;
    float4 v = *(const float4*)(W_ih + (size_t)j * (2 * NE) + koff + k4 * 4);
    ushort4 o;
    o.x = f2bf(v.x); o.y = f2bf(v.y); o.z = f2bf(v.z); o.w = f2bf(v.w);
    *(ushort4*)(dst + (size_t)j * NE + k4 * 4) = o;
}

// ---------- zero pad column preds[:,30,:] + zero scratch ----------------------
__global__ void pad_k(float* __restrict__ out) {
    int gid = blockIdx.x * 256 + threadIdx.x;
    if (gid < NB * NV) {
        int b = gid / NV, v = gid % NV;
        out[(size_t)b * PRED_B + (size_t)NT * NV + v] = 0.f;
    }
}
__global__ void zero_k(float* __restrict__ p, int n) {
    int i = blockIdx.x * 256 + threadIdx.x;
    if (i < n) p[i] = 0.f;
}

// ---------- bf16 MFMA GEMM, B-panel-in-LDS-once, A direct global --------------
// C(MxN) = A(MxK=512) @ B(NxK=512)^T.  Tile 128x128, 4 waves (2x2), wave 64x64.
// AMODE 0: A row m from Abf.  AMODE 1: A row m = Aemb + ridx[min(m,Mact-1)]*512.
// EPI 0: outb[m*N+n] = bf16(v + gxf[(rowlist[m]&255)*N + n])   (masked m<Mact)
// EPI 1: preds scatter via rowlist + rowsum exp-atomics (masked)
// EPI 3: outf[m*N+n] = v + bias1[n] + bias2[n]
template <int AMODE, int EPI>
__launch_bounds__(256)
__global__ void bgemm(const unsigned short* __restrict__ Abf,
                      const int* __restrict__ ridx,
                      const unsigned short* __restrict__ Aemb,
                      const unsigned short* __restrict__ Bbf,
                      int N,
                      const int* __restrict__ mact_p,
                      const float* __restrict__ bias1,
                      const float* __restrict__ bias2,
                      const int* __restrict__ rowlist,
                      float* __restrict__ outf,
                      unsigned short* __restrict__ outb,
                      float* __restrict__ rowsum) {
    __shared__ __align__(16) char Bs[131072];   // [128][512] bf16, XOR-swizzled
    int Mact = mact_p ? *mact_p : (1 << 30);
    int m0 = blockIdx.y * 128;
    if (m0 >= Mact) return;
    int n0 = blockIdx.x * 128;
    int tid = threadIdx.x;
    int lane = tid & 63, w = tid >> 6;
    int wy = w >> 1, wx = w & 1;

    // stage full B panel once
#pragma unroll 4
    for (int p = 0; p < 32; ++p) {
        int row = (tid >> 6) + (p << 2);
        int bn = n0 + row; if (bn > N - 1) bn = N - 1;
        uint4 v = *(const uint4*)(Bbf + ((size_t)bn << 9) + ((tid & 63) << 3));
        int ba = (row << 10) + ((tid & 63) << 4); ba ^= (row & 7) << 4;
        *(uint4*)(Bs + ba) = v;
    }

    // A row pointers for this wave's 4 row-tiles
    const unsigned short* aptr[4];
#pragma unroll
    for (int rt = 0; rt < 4; ++rt) {
        int m = m0 + (wy << 6) + (rt << 4) + (lane & 15);
        if (AMODE == 0) aptr[rt] = Abf + ((size_t)m << 9);
        else {
            int mm = m < Mact ? m : (Mact - 1);
            aptr[rt] = Aemb + ((size_t)ridx[mm] << 9);
        }
    }

    f32x4 acc[4][4];
#pragma unroll
    for (int i = 0; i < 4; ++i)
#pragma unroll
        for (int j = 0; j < 4; ++j) acc[i][j] = (f32x4){0.f, 0.f, 0.f, 0.f};

    __syncthreads();

#pragma unroll 4
    for (int ks = 0; ks < 16; ++ks) {
        int koff = (ks << 5) + ((lane >> 4) << 3);
        bf16x8 bq[4];
#pragma unroll
        for (int ct = 0; ct < 4; ++ct) {
            int brow = (wx << 6) + (ct << 4) + (lane & 15);
            int bb = (brow << 10) + (koff << 1); bb ^= (brow & 7) << 4;
            bq[ct] = *(const bf16x8*)(Bs + bb);
        }
#pragma unroll
        for (int rt = 0; rt < 4; ++rt) {
            bf16x8 aq = *(const bf16x8*)(aptr[rt] + koff);
#pragma unroll
            for (int ct = 0; ct < 4; ++ct)
                acc[rt][ct] = __builtin_amdgcn_mfma_f32_16x16x32_bf16(aq, bq[ct], acc[rt][ct], 0, 0, 0);
        }
    }

    // epilogue; D frag: col = lane&15, row = (lane>>4)*4 + ri
#pragma unroll
    for (int rt = 0; rt < 4; ++rt) {
        float es4[4] = {0.f, 0.f, 0.f, 0.f};
#pragma unroll
        for (int ct = 0; ct < 4; ++ct) {
            int n = n0 + (wx << 6) + (ct << 4) + (lane & 15);
            bool okn = (n < N);
            float badd = 0.f;
            if (EPI == 3) badd = bias1[n] + bias2[n];
            else if (EPI == 1) badd = okn ? bias1[n] : 0.f;
#pragma unroll
            for (int ri = 0; ri < 4; ++ri) {
                int m = m0 + (wy << 6) + (rt << 4) + ((lane >> 4) << 2) + ri;
                float v = acc[rt][ct][ri] + badd;
                if (EPI == 3) {
                    outf[(size_t)m * N + n] = v;
                } else if (EPI == 0) {
                    if (m < Mact) {
                        int b = rowlist[m] & 255;
                        v += bias1[(size_t)b * NG + n];   // fold gx (incl. biases)
                        outb[(size_t)m * N + n] = f2bf(v);
                    }
                } else {
                    if (okn && m < Mact) {
                        int r = rowlist[m];
                        outf[(size_t)(r & 255) * PRED_B + (size_t)(r >> 8) * NV + n] = v;
                        es4[ri] += __expf(v);
                    }
                }
            }
        }
        if (EPI == 1) {
#pragma unroll
            for (int ri = 0; ri < 4; ++ri) {
                float s = es4[ri];
                s += __shfl_xor(s, 1); s += __shfl_xor(s, 2);
                s += __shfl_xor(s, 4); s += __shfl_xor(s, 8);
                if ((lane & 15) == 0) {
                    int m = m0 + (wy << 6) + (rt << 4) + ((lane >> 4) << 2) + ri;
                    if (m < Mact) atomicAdd(&rowsum[m], s);
                }
            }
        }
    }
}

// ---------- fused LSTM recurrence: batch-partitioned, zero inter-block sync ---
// 16 blocks x 512 threads (8 waves). Block g owns batch rows [16g, 16g+16).
// h in LDS (bf16, XOR-swizzled, A-frag layout), c in registers.
// Wave w owns d-tiles {w, w+8, w+16, w+24}; for each, all 4 gate quarters ->
// i/f/g/o of one (row,d) land in the same lane: elementwise is register-local.
// W_hh read direct global->VGPR (2 MB, L2-resident). gallc (= x-side preacts
// incl. gx+biases) staged to LDS per step. Early-exit when cnt_t <= 16g.
__launch_bounds__(512)
__global__ void lstm16_k(const unsigned short* __restrict__ Whb,   // [2048][512]
                         const unsigned short* __restrict__ gallc, // [n_active][2048]
                         unsigned short* __restrict__ h_allc,      // [n_active][512]
                         const int* __restrict__ cnt,
                         const int* __restrict__ start) {
    __shared__ __align__(16) unsigned short hs[16 * 512];   // 16 KB, swizzled
    __shared__ __align__(16) unsigned short gs[16 * 2048];  // 64 KB, linear
    char* hs_c = (char*)hs;
    int tid = threadIdx.x, g = blockIdx.x;
    int lane = tid & 63, w = tid >> 6;
    int hi = lane >> 4, lo = lane & 15;

    // zero h state
    {
        uint4 z = make_uint4(0u, 0u, 0u, 0u);
        *(uint4*)(hs + tid * 16) = z;
        *(uint4*)(hs + tid * 16 + 8) = z;
    }

    // W_hh element offsets for this lane's 16 column-tiles
    size_t boff[4][4];
#pragma unroll
    for (int ti = 0; ti < 4; ++ti)
#pragma unroll
        for (int q = 0; q < 4; ++q) {
            int gcol = q * 512 + ((w + ti * 8) << 4) + lo;
            boff[ti][q] = ((size_t)gcol << 9) + (hi << 3);
        }

    float creg[4][4];
#pragma unroll
    for (int ti = 0; ti < 4; ++ti)
#pragma unroll
        for (int ri = 0; ri < 4; ++ri) creg[ti][ri] = 0.f;

    int srr = tid >> 5, sc = tid & 31;   // staging map: row, 16B-chunk group

    for (int t = 0; t < NT; ++t) {
        int cnt_t = cnt[t];
        if (g * 16 >= cnt_t) break;
        int pos0 = start[t] + g * 16;

        // stage this step's x-side pre-activations (active rows only)
        if (g * 16 + srr < cnt_t) {
            const unsigned short* src = gallc + (size_t)(pos0 + srr) * NG;
            unsigned short* dst = gs + srr * NG;
#pragma unroll
            for (int i = 0; i < 8; ++i) {
                int e = (sc + (i << 5)) << 3;
                *(uint4*)(dst + e) = *(const uint4*)(src + e);
            }
        }
        __syncthreads();

        f32x4 acc[4][4];
#pragma unroll
        for (int ti = 0; ti < 4; ++ti)
#pragma unroll
            for (int q = 0; q < 4; ++q) acc[ti][q] = (f32x4){0.f, 0.f, 0.f, 0.f};

        if (t > 0) {
#pragma unroll 4
            for (int ks = 0; ks < 16; ++ks) {
                int koff = (ks << 5) + (hi << 3);
                int ab = (lo << 10) + (koff << 1); ab ^= (lo & 7) << 4;
                bf16x8 aq = *(const bf16x8*)(hs_c + ab);
#pragma unroll
                for (int ti = 0; ti < 4; ++ti) {
                    bf16x8 bq[4];
#pragma unroll
                    for (int q = 0; q < 4; ++q)
                        bq[q] = *(const bf16x8*)(Whb + boff[ti][q] + (ks << 5));
#pragma unroll
                    for (int q = 0; q < 4; ++q)
                        acc[ti][q] = __builtin_amdgcn_mfma_f32_16x16x32_bf16(aq, bq[q], acc[ti][q], 0, 0, 0);
                }
            }
        }
        __syncthreads();   // all A-reads done before hs overwrite

        // elementwise LSTM cell, fully register-local per lane
#pragma unroll
        for (int ti = 0; ti < 4; ++ti) {
            int d = ((w + ti * 8) << 4) + lo;
#pragma unroll
            for (int ri = 0; ri < 4; ++ri) {
                int row = (hi << 2) + ri;
                bool act = (g * 16 + row) < cnt_t;
                const unsigned short* gr = gs + row * NG;
                float iv = acc[ti][0][ri] + bf2f(gr[d]);
                float fv = acc[ti][1][ri] + bf2f(gr[512 + d]);
                float gv = acc[ti][2][ri] + bf2f(gr[1024 + d]);
                float ov = acc[ti][3][ri] + bf2f(gr[1536 + d]);
                float i_ = 1.f / (1.f + __expf(-iv));
                float f_ = 1.f / (1.f + __expf(-fv));
                float o_ = 1.f / (1.f + __expf(-ov));
                float ea = __expf(-2.f * fabsf(gv));
                float th = (1.f - ea) / (1.f + ea);
                th = (gv < 0.f) ? -th : th;
                float cn = f_ * creg[ti][ri] + i_ * th;
                float ec = __expf(-2.f * fabsf(cn));
                float tc = (1.f - ec) / (1.f + ec);
                tc = (cn < 0.f) ? -tc : tc;
                float hn = o_ * tc;
                if (act) {
                    creg[ti][ri] = cn;
                    unsigned short hb16 = f2bf(hn);
                    int hbb = (row << 10) + (d << 1); hbb ^= (row & 7) << 4;
                    *(unsigned short*)(hs_c + hbb) = hb16;
                    h_allc[(size_t)(pos0 + row) * NH + d] = hb16;
                }
            }
        }
        __syncthreads();   // gs/hs reads done before next step's staging
    }
}

// ---------- final pass: preds = logit - log(rowsum), zero inactive ------------
__global__ void norm_k(float* __restrict__ out, const float* __restrict__ rowsum,
                       const int* __restrict__ cnt, const int* __restrict__ start) {
    int r = blockIdx.x;          // 0..7679, r = t*256+b
    int t = r >> 8, b = r & 255;
    bool act = b < cnt[t];
    float lse = 0.f;
    if (act) lse = logf(rowsum[start[t] + b]);
    float4* row = (float4*)(out + (size_t)b * PRED_B + (size_t)t * NV);
    for (int v4 = threadIdx.x; v4 < NV / 4; v4 += 256) {
        float4 x;
        if (act) {
            x = row[v4];
            x.x -= lse; x.y -= lse; x.z -= lse; x.w -= lse;
        } else {
            x.x = 0.f; x.y = 0.f; x.z = 0.f; x.w = 0.f;
        }
        row[v4] = x;
    }
}

extern "C" void kernel_launch(void* const* d_in, const int* in_sizes, int n_in,
                              void* d_out, int out_size, void* d_ws, size_t ws_size,
                              hipStream_t stream) {
    const float* gimg  = (const float*)d_in[0];
    const int*   w_in  = (const int*)d_in[1];
    const int*   lens  = (const int*)d_in[2];
    const float* emb   = (const float*)d_in[3];
    const float* W_ih  = (const float*)d_in[4];
    const float* W_hh  = (const float*)d_in[5];
    const float* b_ih  = (const float*)d_in[6];
    const float* b_hh  = (const float*)d_in[7];
    const float* W_out = (const float*)d_in[8];
    const float* b_out = (const float*)d_in[9];
    float* out = (float*)d_out;

    char* p = (char*)d_ws;
    auto alloc = [&](size_t bytes) -> char* {
        char* r = p;
        p += (bytes + 255) & ~(size_t)255;
        return r;
    };
    int*   order   = (int*)alloc(NB * 4);
    int*   wsort   = (int*)alloc(NB * ML * 4);
    int*   cnt     = (int*)alloc(NT * 4);
    int*   start   = (int*)alloc((NT + 1) * 4);
    int*   rowlist = (int*)alloc((size_t)NT * NB * 4);
    int*   rowwc   = (int*)alloc((size_t)NT * NB * 4);
    float* gx      = (float*)alloc((size_t)NB * NG * 4);
    float* rowsum  = (float*)alloc((size_t)NT * NB * 4);
    unsigned short* g_sb   = (unsigned short*)alloc((size_t)NB * NE * 2);
    unsigned short* h_allc = (unsigned short*)alloc((size_t)NT * NB * NH * 2);
    unsigned short* Whb    = (unsigned short*)alloc((size_t)NG * NH * 2);
    unsigned short* Wxl    = (unsigned short*)alloc((size_t)NG * NE * 2);
    unsigned short* Wxb    = (unsigned short*)alloc((size_t)NG * NE * 2);
    unsigned short* Wob    = (unsigned short*)alloc((size_t)NV * NH * 2);
    unsigned short* embb   = (unsigned short*)alloc((size_t)NV * NE * 2);
    unsigned short* gallc  = (unsigned short*)alloc((size_t)NT * NB * NG * 2);
    int* nact = start + NT;   // n_active lives at start[30]

    sort_k<<<1, 256, 0, stream>>>(lens, order, cnt, start, out + OFF_DEC);
    gather_k<<<NB, 256, 0, stream>>>(gimg, w_in, order, g_sb, wsort, out + OFF_TGT);
    rowlist_k<<<NT, 256, 0, stream>>>(wsort, cnt, start, rowlist, rowwc);
    f2b_k<<<(NG * NH / 4 + 255) / 256, 256, 0, stream>>>(W_hh, Whb, NG * NH / 4);
    wih_k<<<(NG * NE / 4 + 255) / 256, 256, 0, stream>>>(W_ih, Wxl, 0);
    wih_k<<<(NG * NE / 4 + 255) / 256, 256, 0, stream>>>(W_ih, Wxb, NE);
    f2b_k<<<(NV * NH / 4 + 255) / 256, 256, 0, stream>>>(W_out, Wob, NV * NH / 4);
    f2b_k<<<(NV * NE / 4 + 255) / 256, 256, 0, stream>>>(emb, embb, NV * NE / 4);
    pad_k<<<(NB * NV + 255) / 256, 256, 0, stream>>>(out);
    zero_k<<<(NT * NB + 255) / 256, 256, 0, stream>>>(rowsum, NT * NB);

    // gx = g_sb @ Wxl^T + b_ih + b_hh     (256 x 2048, K=512, fp32 out)
    bgemm<0, 3><<<dim3(NG / 128, NB / 128), 256, 0, stream>>>(
        g_sb, nullptr, nullptr, Wxl, NG, nullptr,
        b_ih, b_hh, nullptr, gx, nullptr, nullptr);

    // gallc[pos] = bf16( emb[rowwc[pos]] @ Wxb^T + gx[b] )   (n_active x 2048)
    bgemm<1, 0><<<dim3(NG / 128, NT * NB / 128), 256, 0, stream>>>(
        nullptr, rowwc, embb, Wxb, NG, nact,
        gx, nullptr, rowlist, nullptr, gallc, nullptr);

    // fused 30-step recurrence: batch-partitioned, no inter-block sync
    lstm16_k<<<16, 512, 0, stream>>>(Whb, gallc, h_allc, cnt, start);

    // logits = h_allc @ Wob^T + b_out -> preds scatter + rowsum exp-atomics
    bgemm<0, 1><<<dim3((NV + 127) / 128, NT * NB / 128), 256, 0, stream>>>(
        h_allc, nullptr, nullptr, Wob, NV, nact,
        b_out, nullptr, rowlist, out, nullptr, rowsum);

    norm_k<<<NT * NB, 256, 0, stream>>>(out, rowsum, cnt, start);
}

// Round 5
// 1406.137 us; speedup vs baseline: 1.6467x; 1.6467x over previous
//
#include <hip/hip_runtime.h>
#include <hip/hip_bf16.h>
#include <math.h>

// Problem constants
#define NB   256      // batch
#define ML   31       // MAX_LEN
#define NT   30       // T = MAX_LEN-1 decode steps
#define NV   10000    // vocab
#define NH   512      // hidden
#define NE   512      // embed
#define NG   2048     // 4*H gates

// Output layout (floats): preds (256,31,10000) | target (256,30) | dec_len (256,)
#define OFF_TGT  (256LL*31LL*10000LL)
#define OFF_DEC  (OFF_TGT + 256LL*30LL)
#define PRED_B   (31LL*10000LL)

typedef __attribute__((ext_vector_type(8))) short bf16x8;
typedef __attribute__((ext_vector_type(4))) float f32x4;

__device__ inline unsigned short f2bf(float f) {
    unsigned int x = __float_as_uint(f);
    unsigned int r = x + 0x7FFFu + ((x >> 16) & 1u);   // RNE
    return (unsigned short)(r >> 16);
}
__device__ inline float bf2f(unsigned short u) {
    return __uint_as_float((unsigned int)u << 16);
}

__device__ inline void gl2lds16(const void* g, void* l) {
    __builtin_amdgcn_global_load_lds(
        (const __attribute__((address_space(1))) unsigned int*)g,
        (__attribute__((address_space(3))) unsigned int*)l, 16, 0, 0);
}

// ---------- sort: stable descending argsort + per-step active counts ----------
__global__ void sort_k(const int* __restrict__ lens, int* __restrict__ order,
                       int* __restrict__ cnt, int* __restrict__ start,
                       float* __restrict__ out_dec) {
    __shared__ int sd[NB];
    int i = threadIdx.x;
    int li = lens[i];
    int r = 0;
    for (int j = 0; j < NB; j++) {
        int lj = lens[j];
        r += (lj > li) || (lj == li && j < i);
    }
    order[r] = i;
    out_dec[r] = (float)(li - 1);
    sd[r] = li - 1;
    __syncthreads();
    if (i < NT) {
        int c = 0;
        for (int b = 0; b < NB; b++) c += (sd[b] > i);
        cnt[i] = c;
    }
    __syncthreads();
    if (i == 0) {
        int s = 0;
        for (int t = 0; t < NT; t++) { start[t] = s; s += cnt[t]; }
        start[NT] = s;                 // n_active
    }
}

// ---------- gather sorted rows (bf16 image), emit target ----------------------
__global__ void gather_k(const float* __restrict__ gimg, const int* __restrict__ w_in,
                         const int* __restrict__ order,
                         unsigned short* __restrict__ g_sb, int* __restrict__ wsort,
                         float* __restrict__ out_tgt) {
    int r = blockIdx.x, tid = threadIdx.x;
    int o = order[r];
    for (int e = tid; e < NE; e += 256)
        g_sb[r * NE + e] = f2bf(gimg[o * NE + e]);
    if (tid < ML) wsort[r * ML + tid] = w_in[o * ML + tid];
    if (tid < NT) out_tgt[r * NT + tid] = (float)w_in[o * ML + tid + 1];
}

// ---------- compact active-row lists ------------------------------------------
__global__ void rowlist_k(const int* __restrict__ wsort, const int* __restrict__ cnt,
                          const int* __restrict__ start,
                          int* __restrict__ rowlist, int* __restrict__ rowwc) {
    int t = blockIdx.x, b = threadIdx.x;
    if (b < cnt[t]) {
        int pos = start[t] + b;
        rowlist[pos] = t * 256 + b;
        rowwc[pos] = wsort[b * ML + t];
    }
}

// ---------- fp32 -> bf16 conversions ------------------------------------------
__global__ void f2b_k(const float* __restrict__ src, unsigned short* __restrict__ dst, int n4) {
    int i = blockIdx.x * 256 + threadIdx.x;
    if (i >= n4) return;
    float4 v = ((const float4*)src)[i];
    ushort4 o;
    o.x = f2bf(v.x); o.y = f2bf(v.y); o.z = f2bf(v.z); o.w = f2bf(v.w);
    ((ushort4*)dst)[i] = o;
}

// dst[j][k] = bf16(W_ih[j][koff+k]), j<2048, k<512
__global__ void wih_k(const float* __restrict__ W_ih, unsigned short* __restrict__ dst, int koff) {
    int gid = blockIdx.x * 256 + threadIdx.x;   // 2048*128 float4 chunks
    int j = gid >> 7, k4 = gid & 127;
    float4 v = *(const float4*)(W_ih + (size_t)j * (2 * NE) + koff + k4 * 4);
    ushort4 o;
    o.x = f2bf(v.x); o.y = f2bf(v.y); o.z = f2bf(v.z); o.w = f2bf(v.w);
    *(ushort4*)(dst + (size_t)j * NE + k4 * 4) = o;
}

// ---------- W_hh -> Wimg: 32 chunks x 64KB, swizzled-LDS-image layout ---------
// Chunk ch=(kc,half): kc=ch>>1 covers K [kc*32,kc*32+32), half=ch&1 covers gate
// quarters q in {2*half, 2*half+1}. Within chunk: R in [0,1024) indexes cols:
// w=R>>7, ct=(R>>4)&7, lo=R&15 -> q=2*half+(ct>>2), d=w*64+(ct&3)*16+lo,
// col c=q*512+d. Byte addr: (R*64 + hi*16) ^ ((lo&7)<<4), hi=k-subchunk 0..3.
__global__ void wimg_k(const float* __restrict__ W_hh, unsigned short* __restrict__ Wimg) {
    int gid = blockIdx.x * 256 + threadIdx.x;   // 131072 = 32ch * 1024R * 4hi
    int hi = gid & 3, R = (gid >> 2) & 1023, ch = gid >> 12;
    int kc = ch >> 1, half = ch & 1;
    int w = R >> 7, ct = (R >> 4) & 7, lo = R & 15;
    int q = half * 2 + (ct >> 2);
    int d = w * 64 + (ct & 3) * 16 + lo;
    int c = q * 512 + d;
    int k = kc * 32 + hi * 8;
    const float* src = W_hh + (size_t)c * NH + k;
    __align__(16) unsigned short o[8];
#pragma unroll
    for (int j = 0; j < 8; ++j) o[j] = f2bf(src[j]);
    int ba = (R * 64 + hi * 16) ^ ((lo & 7) << 4);
    *(uint4*)((char*)Wimg + ((size_t)ch << 16) + ba) = *(const uint4*)o;
}

// ---------- zero pad column preds[:,30,:] + zero scratch ----------------------
__global__ void pad_k(float* __restrict__ out) {
    int gid = blockIdx.x * 256 + threadIdx.x;
    if (gid < NB * NV) {
        int b = gid / NV, v = gid % NV;
        out[(size_t)b * PRED_B + (size_t)NT * NV + v] = 0.f;
    }
}
__global__ void zero_k(float* __restrict__ p, int n) {
    int i = blockIdx.x * 256 + threadIdx.x;
    if (i < n) p[i] = 0.f;
}

// ---------- bf16 MFMA GEMM, B-panel-in-LDS-once, A direct global --------------
// C(MxN) = A(MxK=512) @ B(NxK=512)^T.  Tile 128x128, 4 waves (2x2), wave 64x64.
// AMODE 0: A row m from Abf.  AMODE 1: A row m = Aemb + ridx[min(m,Mact-1)]*512.
// EPI 0: outb[m][d*4+q] = bf16(v + gx[b][n])   (n = q*512+d; masked m<Mact)
// EPI 1: preds scatter via rowlist + rowsum exp-atomics (masked)
// EPI 3: outf[m*N+n] = v + bias1[n] + bias2[n]
template <int AMODE, int EPI>
__launch_bounds__(256)
__global__ void bgemm(const unsigned short* __restrict__ Abf,
                      const int* __restrict__ ridx,
                      const unsigned short* __restrict__ Aemb,
                      const unsigned short* __restrict__ Bbf,
                      int N,
                      const int* __restrict__ mact_p,
                      const float* __restrict__ bias1,
                      const float* __restrict__ bias2,
                      const int* __restrict__ rowlist,
                      float* __restrict__ outf,
                      unsigned short* __restrict__ outb,
                      float* __restrict__ rowsum) {
    __shared__ __align__(16) char Bs[131072];   // [128][512] bf16, XOR-swizzled
    int Mact = mact_p ? *mact_p : (1 << 30);
    int m0 = blockIdx.y * 128;
    if (m0 >= Mact) return;
    int n0 = blockIdx.x * 128;
    int tid = threadIdx.x;
    int lane = tid & 63, w = tid >> 6;
    int wy = w >> 1, wx = w & 1;

    // stage full B panel once
#pragma unroll 4
    for (int p = 0; p < 32; ++p) {
        int row = (tid >> 6) + (p << 2);
        int bn = n0 + row; if (bn > N - 1) bn = N - 1;
        uint4 v = *(const uint4*)(Bbf + ((size_t)bn << 9) + ((tid & 63) << 3));
        int ba = (row << 10) + ((tid & 63) << 4); ba ^= (row & 7) << 4;
        *(uint4*)(Bs + ba) = v;
    }

    // A row pointers for this wave's 4 row-tiles
    const unsigned short* aptr[4];
#pragma unroll
    for (int rt = 0; rt < 4; ++rt) {
        int m = m0 + (wy << 6) + (rt << 4) + (lane & 15);
        if (AMODE == 0) aptr[rt] = Abf + ((size_t)m << 9);
        else {
            int mm = m < Mact ? m : (Mact - 1);
            aptr[rt] = Aemb + ((size_t)ridx[mm] << 9);
        }
    }

    f32x4 acc[4][4];
#pragma unroll
    for (int i = 0; i < 4; ++i)
#pragma unroll
        for (int j = 0; j < 4; ++j) acc[i][j] = (f32x4){0.f, 0.f, 0.f, 0.f};

    __syncthreads();

#pragma unroll 4
    for (int ks = 0; ks < 16; ++ks) {
        int koff = (ks << 5) + ((lane >> 4) << 3);
        bf16x8 bq[4];
#pragma unroll
        for (int ct = 0; ct < 4; ++ct) {
            int brow = (wx << 6) + (ct << 4) + (lane & 15);
            int bb = (brow << 10) + (koff << 1); bb ^= (brow & 7) << 4;
            bq[ct] = *(const bf16x8*)(Bs + bb);
        }
#pragma unroll
        for (int rt = 0; rt < 4; ++rt) {
            bf16x8 aq = *(const bf16x8*)(aptr[rt] + koff);
#pragma unroll
            for (int ct = 0; ct < 4; ++ct)
                acc[rt][ct] = __builtin_amdgcn_mfma_f32_16x16x32_bf16(aq, bq[ct], acc[rt][ct], 0, 0, 0);
        }
    }

    // epilogue; D frag: col = lane&15, row = (lane>>4)*4 + ri
#pragma unroll
    for (int rt = 0; rt < 4; ++rt) {
        float es4[4] = {0.f, 0.f, 0.f, 0.f};
#pragma unroll
        for (int ct = 0; ct < 4; ++ct) {
            int n = n0 + (wx << 6) + (ct << 4) + (lane & 15);
            bool okn = (n < N);
            float badd = 0.f;
            if (EPI == 3) badd = bias1[n] + bias2[n];
            else if (EPI == 1) badd = okn ? bias1[n] : 0.f;
#pragma unroll
            for (int ri = 0; ri < 4; ++ri) {
                int m = m0 + (wy << 6) + (rt << 4) + ((lane >> 4) << 2) + ri;
                float v = acc[rt][ct][ri] + badd;
                if (EPI == 3) {
                    outf[(size_t)m * N + n] = v;
                } else if (EPI == 0) {
                    if (m < Mact) {
                        int b = rowlist[m] & 255;
                        v += bias1[(size_t)b * NG + n];   // fold gx (incl. biases)
                        outb[(size_t)m * NG + ((n & 511) << 2) + (n >> 9)] = f2bf(v);
                    }
                } else {
                    if (okn && m < Mact) {
                        int r = rowlist[m];
                        outf[(size_t)(r & 255) * PRED_B + (size_t)(r >> 8) * NV + n] = v;
                        es4[ri] += __expf(v);
                    }
                }
            }
        }
        if (EPI == 1) {
#pragma unroll
            for (int ri = 0; ri < 4; ++ri) {
                float s = es4[ri];
                s += __shfl_xor(s, 1); s += __shfl_xor(s, 2);
                s += __shfl_xor(s, 4); s += __shfl_xor(s, 8);
                if ((lane & 15) == 0) {
                    int m = m0 + (wy << 6) + (rt << 4) + ((lane >> 4) << 2) + ri;
                    if (m < Mact) atomicAdd(&rowsum[m], s);
                }
            }
        }
    }
}

// ---------- fused LSTM recurrence: batch-partitioned + DMA-pipelined W --------
// 16 blocks x 512 threads (8 waves). Block g owns batch rows [16g, 16g+16).
// h in LDS (bf16, XOR-swizzled A-frag layout), c in registers.
// W streamed per step as 32 chunks of 64KB via global_load_lds, double-buffered,
// counted vmcnt (T3/T4).  Wave w owns h-dims d in [64w, 64w+64); the Wimg
// column permutation puts i/f/g/o of each (row,d) in the same lane.
// gallc layout: [pos][d][4 quarters] -> one 8B read per (row,d).
__launch_bounds__(512)
__global__ void lstmws_k(const unsigned short* __restrict__ Wimg,   // [32][64KB]
                         const unsigned short* __restrict__ gallc,  // [n_active][512][4]
                         unsigned short* __restrict__ h_allc,       // [n_active][512]
                         const int* __restrict__ cnt,
                         const int* __restrict__ start) {
    __shared__ __align__(16) char Wbuf[2][65536];
    __shared__ __align__(16) unsigned short hs[16 * 512];
    char* hs_c = (char*)hs;
    int tid = threadIdx.x, g = blockIdx.x;
    int lane = tid & 63, w = tid >> 6;
    int hi = lane >> 4, lo = lane & 15;

    // zero h state
    {
        uint4 z = make_uint4(0u, 0u, 0u, 0u);
        *(uint4*)(hs + tid * 16) = z;
        *(uint4*)(hs + tid * 16 + 8) = z;
    }
    __syncthreads();

    float creg[4][4];
#pragma unroll
    for (int dt = 0; dt < 4; ++dt)
#pragma unroll
        for (int ri = 0; ri < 4; ++ri) creg[dt][ri] = 0.f;

    auto issue8 = [&](int ch, int buf) {
        const char* gsrc = (const char*)Wimg + ((size_t)ch << 16) + tid * 16;
        char* ldst = Wbuf[buf] + w * 1024;
#pragma unroll
        for (int r = 0; r < 8; ++r)
            gl2lds16(gsrc + r * 8192, ldst + r * 8192);
    };

    for (int t = 0; t < NT; ++t) {
        int cnt_t = cnt[t];
        if (g * 16 >= cnt_t) break;
        int pos0 = start[t] + g * 16;
        int nrow = cnt_t - g * 16; if (nrow > 16) nrow = 16;

        issue8(0, 0);               // stage chunk 0

        // prefetch x-side pre-activations (one 8B chunk per (row,d))
        uint2 gv[4][4];
#pragma unroll
        for (int ri = 0; ri < 4; ++ri) {
            int row = hi * 4 + ri;
            int rr = row < nrow ? row : nrow - 1;
            const unsigned short* gp = gallc + ((size_t)(pos0 + rr) << 11);
#pragma unroll
            for (int dt = 0; dt < 4; ++dt) {
                int d = w * 64 + dt * 16 + lo;
                gv[dt][ri] = *(const uint2*)(gp + d * 4);
            }
        }

        f32x4 acc[2][8];
#pragma unroll
        for (int hh = 0; hh < 2; ++hh)
#pragma unroll
            for (int ct = 0; ct < 8; ++ct) acc[hh][ct] = (f32x4){0.f, 0.f, 0.f, 0.f};

        for (int kc = 0; kc < 16; ++kc) {
            int koff = (kc << 5) + (hi << 3);
            int ab = (lo << 10) + (koff << 1); ab ^= (lo & 7) << 4;
#pragma unroll
            for (int half = 0; half < 2; ++half) {
                int ch = kc * 2 + half;
                int cb = ch & 1;
                if (ch < 31) {
                    issue8(ch + 1, cb ^ 1);
                    asm volatile("s_waitcnt vmcnt(8)" ::: "memory");
                } else {
                    asm volatile("s_waitcnt vmcnt(0)" ::: "memory");
                }
                __builtin_amdgcn_s_barrier();
                asm volatile("" ::: "memory");
                bf16x8 aq = *(const bf16x8*)(hs_c + ab);
#pragma unroll
                for (int ct = 0; ct < 8; ++ct) {
                    int ba = (((w * 8 + ct) * 16 + lo) * 64 + hi * 16) ^ ((lo & 7) << 4);
                    bf16x8 bq = *(const bf16x8*)(Wbuf[cb] + ba);
                    acc[half][ct] = __builtin_amdgcn_mfma_f32_16x16x32_bf16(aq, bq, acc[half][ct], 0, 0, 0);
                }
                asm volatile("s_waitcnt lgkmcnt(0)" ::: "memory");
                __builtin_amdgcn_s_barrier();
                asm volatile("" ::: "memory");
            }
        }

        // elementwise LSTM cell, fully register-local per lane
#pragma unroll
        for (int dt = 0; dt < 4; ++dt) {
            int d = w * 64 + dt * 16 + lo;
#pragma unroll
            for (int ri = 0; ri < 4; ++ri) {
                int row = hi * 4 + ri;
                bool act = row < nrow;
                const unsigned short* gq = (const unsigned short*)&gv[dt][ri];
                float iv = acc[0][dt][ri]     + bf2f(gq[0]);
                float fv = acc[0][4 + dt][ri] + bf2f(gq[1]);
                float gg = acc[1][dt][ri]     + bf2f(gq[2]);
                float ov = acc[1][4 + dt][ri] + bf2f(gq[3]);
                float i_ = 1.f / (1.f + __expf(-iv));
                float f_ = 1.f / (1.f + __expf(-fv));
                float o_ = 1.f / (1.f + __expf(-ov));
                float ea = __expf(-2.f * fabsf(gg));
                float th = (1.f - ea) / (1.f + ea);
                th = (gg < 0.f) ? -th : th;
                float cn = f_ * creg[dt][ri] + i_ * th;
                float ec = __expf(-2.f * fabsf(cn));
                float tc = (1.f - ec) / (1.f + ec);
                tc = (cn < 0.f) ? -tc : tc;
                float hn = o_ * tc;
                if (act) {
                    creg[dt][ri] = cn;
                    unsigned short hb16 = f2bf(hn);
                    int hbb = (row << 10) + (d << 1); hbb ^= (row & 7) << 4;
                    *(unsigned short*)(hs_c + hbb) = hb16;
                    h_allc[(size_t)(pos0 + row) * NH + d] = hb16;
                }
            }
        }
        asm volatile("s_waitcnt lgkmcnt(0)" ::: "memory");
        __builtin_amdgcn_s_barrier();
        asm volatile("" ::: "memory");
    }
}

// ---------- final pass: preds = logit - log(rowsum), zero inactive ------------
__global__ void norm_k(float* __restrict__ out, const float* __restrict__ rowsum,
                       const int* __restrict__ cnt, const int* __restrict__ start) {
    int r = blockIdx.x;          // 0..7679, r = t*256+b
    int t = r >> 8, b = r & 255;
    bool act = b < cnt[t];
    float lse = 0.f;
    if (act) lse = logf(rowsum[start[t] + b]);
    float4* row = (float4*)(out + (size_t)b * PRED_B + (size_t)t * NV);
    for (int v4 = threadIdx.x; v4 < NV / 4; v4 += 256) {
        float4 x;
        if (act) {
            x = row[v4];
            x.x -= lse; x.y -= lse; x.z -= lse; x.w -= lse;
        } else {
            x.x = 0.f; x.y = 0.f; x.z = 0.f; x.w = 0.f;
        }
        row[v4] = x;
    }
}

extern "C" void kernel_launch(void* const* d_in, const int* in_sizes, int n_in,
                              void* d_out, int out_size, void* d_ws, size_t ws_size,
                              hipStream_t stream) {
    const float* gimg  = (const float*)d_in[0];
    const int*   w_in  = (const int*)d_in[1];
    const int*   lens  = (const int*)d_in[2];
    const float* emb   = (const float*)d_in[3];
    const float* W_ih  = (const float*)d_in[4];
    const float* W_hh  = (const float*)d_in[5];
    const float* b_ih  = (const float*)d_in[6];
    const float* b_hh  = (const float*)d_in[7];
    const float* W_out = (const float*)d_in[8];
    const float* b_out = (const float*)d_in[9];
    float* out = (float*)d_out;

    char* p = (char*)d_ws;
    auto alloc = [&](size_t bytes) -> char* {
        char* r = p;
        p += (bytes + 255) & ~(size_t)255;
        return r;
    };
    int*   order   = (int*)alloc(NB * 4);
    int*   wsort   = (int*)alloc(NB * ML * 4);
    int*   cnt     = (int*)alloc(NT * 4);
    int*   start   = (int*)alloc((NT + 1) * 4);
    int*   rowlist = (int*)alloc((size_t)NT * NB * 4);
    int*   rowwc   = (int*)alloc((size_t)NT * NB * 4);
    float* gx      = (float*)alloc((size_t)NB * NG * 4);
    float* rowsum  = (float*)alloc((size_t)NT * NB * 4);
    unsigned short* g_sb   = (unsigned short*)alloc((size_t)NB * NE * 2);
    unsigned short* h_allc = (unsigned short*)alloc((size_t)NT * NB * NH * 2);
    unsigned short* Wimg   = (unsigned short*)alloc((size_t)NG * NH * 2);
    unsigned short* Wxl    = (unsigned short*)alloc((size_t)NG * NE * 2);
    unsigned short* Wxb    = (unsigned short*)alloc((size_t)NG * NE * 2);
    unsigned short* Wob    = (unsigned short*)alloc((size_t)NV * NH * 2);
    unsigned short* embb   = (unsigned short*)alloc((size_t)NV * NE * 2);
    unsigned short* gallc  = (unsigned short*)alloc((size_t)NT * NB * NG * 2);
    int* nact = start + NT;   // n_active lives at start[30]

    sort_k<<<1, 256, 0, stream>>>(lens, order, cnt, start, out + OFF_DEC);
    gather_k<<<NB, 256, 0, stream>>>(gimg, w_in, order, g_sb, wsort, out + OFF_TGT);
    rowlist_k<<<NT, 256, 0, stream>>>(wsort, cnt, start, rowlist, rowwc);
    wimg_k<<<512, 256, 0, stream>>>(W_hh, Wimg);
    wih_k<<<(NG * NE / 4 + 255) / 256, 256, 0, stream>>>(W_ih, Wxl, 0);
    wih_k<<<(NG * NE / 4 + 255) / 256, 256, 0, stream>>>(W_ih, Wxb, NE);
    f2b_k<<<(NV * NH / 4 + 255) / 256, 256, 0, stream>>>(W_out, Wob, NV * NH / 4);
    f2b_k<<<(NV * NE / 4 + 255) / 256, 256, 0, stream>>>(emb, embb, NV * NE / 4);
    pad_k<<<(NB * NV + 255) / 256, 256, 0, stream>>>(out);
    zero_k<<<(NT * NB + 255) / 256, 256, 0, stream>>>(rowsum, NT * NB);

    // gx = g_sb @ Wxl^T + b_ih + b_hh     (256 x 2048, K=512, fp32 out)
    bgemm<0, 3><<<dim3(NG / 128, NB / 128), 256, 0, stream>>>(
        g_sb, nullptr, nullptr, Wxl, NG, nullptr,
        b_ih, b_hh, nullptr, gx, nullptr, nullptr);

    // gallc[pos][d][q] = bf16( emb[rowwc[pos]] @ Wxb^T + gx[b] )   (n_active x 2048)
    bgemm<1, 0><<<dim3(NG / 128, NT * NB / 128), 256, 0, stream>>>(
        nullptr, rowwc, embb, Wxb, NG, nact,
        gx, nullptr, rowlist, nullptr, gallc, nullptr);

    // fused 30-step recurrence: batch-partitioned, DMA-pipelined W streaming
    lstmws_k<<<16, 512, 0, stream>>>(Wimg, gallc, h_allc, cnt, start);

    // logits = h_allc @ Wob^T + b_out -> preds scatter + rowsum exp-atomics
    bgemm<0, 1><<<dim3((NV + 127) / 128, NT * NB / 128), 256, 0, stream>>>(
        h_allc, nullptr, nullptr, Wob, NV, nact,
        b_out, nullptr, rowlist, out, nullptr, rowsum);

    norm_k<<<NT * NB, 256, 0, stream>>>(out, rowsum, cnt, start);
}

// Round 6
// 945.183 us; speedup vs baseline: 2.4498x; 1.4877x over previous
//
#include <hip/hip_runtime.h>
#include <hip/hip_bf16.h>
#include <math.h>

// Problem constants
#define NB   256      // batch
#define ML   31       // MAX_LEN
#define NT   30       // T = MAX_LEN-1 decode steps
#define NV   10000    // vocab
#define NH   512      // hidden
#define NE   512      // embed
#define NG   2048     // 4*H gates

// Output layout (floats): preds (256,31,10000) | target (256,30) | dec_len (256,)
#define OFF_TGT  (256LL*31LL*10000LL)
#define OFF_DEC  (OFF_TGT + 256LL*30LL)
#define PRED_B   (31LL*10000LL)

typedef __attribute__((ext_vector_type(8))) short bf16x8;
typedef __attribute__((ext_vector_type(4))) float f32x4;

__device__ inline unsigned short f2bf(float f) {
    unsigned int x = __float_as_uint(f);
    unsigned int r = x + 0x7FFFu + ((x >> 16) & 1u);   // RNE
    return (unsigned short)(r >> 16);
}
__device__ inline float bf2f(unsigned short u) {
    return __uint_as_float((unsigned int)u << 16);
}

__device__ inline void gl2lds16(const void* g, void* l) {
    __builtin_amdgcn_global_load_lds(
        (const __attribute__((address_space(1))) unsigned int*)g,
        (__attribute__((address_space(3))) unsigned int*)l, 16, 0, 0);
}

// ---------- sort: stable descending argsort + per-step active counts ----------
__global__ void sort_k(const int* __restrict__ lens, int* __restrict__ order,
                       int* __restrict__ cnt, int* __restrict__ start,
                       float* __restrict__ out_dec) {
    __shared__ int sd[NB];
    int i = threadIdx.x;
    int li = lens[i];
    int r = 0;
    for (int j = 0; j < NB; j++) {
        int lj = lens[j];
        r += (lj > li) || (lj == li && j < i);
    }
    order[r] = i;
    out_dec[r] = (float)(li - 1);
    sd[r] = li - 1;
    __syncthreads();
    if (i < NT) {
        int c = 0;
        for (int b = 0; b < NB; b++) c += (sd[b] > i);
        cnt[i] = c;
    }
    __syncthreads();
    if (i == 0) {
        int s = 0;
        for (int t = 0; t < NT; t++) { start[t] = s; s += cnt[t]; }
        start[NT] = s;                 // n_active
    }
}

// ---------- gather sorted rows (bf16 image), emit target ----------------------
__global__ void gather_k(const float* __restrict__ gimg, const int* __restrict__ w_in,
                         const int* __restrict__ order,
                         unsigned short* __restrict__ g_sb, int* __restrict__ wsort,
                         float* __restrict__ out_tgt) {
    int r = blockIdx.x, tid = threadIdx.x;
    int o = order[r];
    for (int e = tid; e < NE; e += 256)
        g_sb[r * NE + e] = f2bf(gimg[o * NE + e]);
    if (tid < ML) wsort[r * ML + tid] = w_in[o * ML + tid];
    if (tid < NT) out_tgt[r * NT + tid] = (float)w_in[o * ML + tid + 1];
}

// ---------- compact active-row lists ------------------------------------------
__global__ void rowlist_k(const int* __restrict__ wsort, const int* __restrict__ cnt,
                          const int* __restrict__ start,
                          int* __restrict__ rowlist, int* __restrict__ rowwc) {
    int t = blockIdx.x, b = threadIdx.x;
    if (b < cnt[t]) {
        int pos = start[t] + b;
        rowlist[pos] = t * 256 + b;
        rowwc[pos] = wsort[b * ML + t];
    }
}

// ---------- fp32 -> bf16 conversions ------------------------------------------
__global__ void f2b_k(const float* __restrict__ src, unsigned short* __restrict__ dst, int n4) {
    int i = blockIdx.x * 256 + threadIdx.x;
    if (i >= n4) return;
    float4 v = ((const float4*)src)[i];
    ushort4 o;
    o.x = f2bf(v.x); o.y = f2bf(v.y); o.z = f2bf(v.z); o.w = f2bf(v.w);
    ((ushort4*)dst)[i] = o;
}

// dst[j][k] = bf16(W_ih[j][koff+k]), j<2048, k<512
__global__ void wih_k(const float* __restrict__ W_ih, unsigned short* __restrict__ dst, int koff) {
    int gid = blockIdx.x * 256 + threadIdx.x;   // 2048*128 float4 chunks
    int j = gid >> 7, k4 = gid & 127;
    float4 v = *(const float4*)(W_ih + (size_t)j * (2 * NE) + koff + k4 * 4);
    ushort4 o;
    o.x = f2bf(v.x); o.y = f2bf(v.y); o.z = f2bf(v.z); o.w = f2bf(v.w);
    *(ushort4*)(dst + (size_t)j * NE + k4 * 4) = o;
}

// ---------- W_hh -> Wimg2: 16 slices x 128KB, swizzled-LDS-image layout -------
// Slice s holds cols {q*512 + s*32 + ct*16 + lo} (q 0..3, ct 0..1, lo 0..15).
// R = (q*2+ct)*16+lo in [0,128). Element (R, kt 0..15, hi 0..3, j 0..7):
// src = W_hh[col][kt*32+hi*8+j]; dst byte = s*131072 + R*1024 +
//       ((kt*64 + hi*16) ^ ((lo&7)<<4)).
__global__ void wimg2_k(const float* __restrict__ W_hh, unsigned short* __restrict__ Wimg2) {
    int gid = blockIdx.x * 256 + threadIdx.x;   // 131072 = 16s * 128R * 16kt * 4hi
    int hi = gid & 3, kt = (gid >> 2) & 15, R = (gid >> 6) & 127, s = gid >> 13;
    int q = R >> 5, ct = (R >> 4) & 1, lo = R & 15;
    int col = q * 512 + s * 32 + ct * 16 + lo;
    int k = kt * 32 + hi * 8;
    const float* src = W_hh + (size_t)col * NH + k;
    __align__(16) unsigned short o[8];
#pragma unroll
    for (int j = 0; j < 8; ++j) o[j] = f2bf(src[j]);
    int ba = (R << 10) + ((kt * 64 + hi * 16) ^ ((lo & 7) << 4));
    *(uint4*)((char*)Wimg2 + ((size_t)s << 17) + ba) = *(const uint4*)o;
}

// ---------- zero pad column preds[:,30,:] + zero scratch ----------------------
__global__ void pad_k(float* __restrict__ out) {
    int gid = blockIdx.x * 256 + threadIdx.x;
    if (gid < NB * NV) {
        int b = gid / NV, v = gid % NV;
        out[(size_t)b * PRED_B + (size_t)NT * NV + v] = 0.f;
    }
}
__global__ void zero_k(float* __restrict__ p, int n) {
    int i = blockIdx.x * 256 + threadIdx.x;
    if (i < n) p[i] = 0.f;
}

// ---------- bf16 MFMA GEMM, B-panel-in-LDS-once, A direct global --------------
template <int AMODE, int EPI>
__launch_bounds__(256)
__global__ void bgemm(const unsigned short* __restrict__ Abf,
                      const int* __restrict__ ridx,
                      const unsigned short* __restrict__ Aemb,
                      const unsigned short* __restrict__ Bbf,
                      int N,
                      const int* __restrict__ mact_p,
                      const float* __restrict__ bias1,
                      const float* __restrict__ bias2,
                      const int* __restrict__ rowlist,
                      float* __restrict__ outf,
                      unsigned short* __restrict__ outb,
                      float* __restrict__ rowsum) {
    __shared__ __align__(16) char Bs[131072];   // [128][512] bf16, XOR-swizzled
    int Mact = mact_p ? *mact_p : (1 << 30);
    int m0 = blockIdx.y * 128;
    if (m0 >= Mact) return;
    int n0 = blockIdx.x * 128;
    int tid = threadIdx.x;
    int lane = tid & 63, w = tid >> 6;
    int wy = w >> 1, wx = w & 1;

#pragma unroll 4
    for (int p = 0; p < 32; ++p) {
        int row = (tid >> 6) + (p << 2);
        int bn = n0 + row; if (bn > N - 1) bn = N - 1;
        uint4 v = *(const uint4*)(Bbf + ((size_t)bn << 9) + ((tid & 63) << 3));
        int ba = (row << 10) + ((tid & 63) << 4); ba ^= (row & 7) << 4;
        *(uint4*)(Bs + ba) = v;
    }

    const unsigned short* aptr[4];
#pragma unroll
    for (int rt = 0; rt < 4; ++rt) {
        int m = m0 + (wy << 6) + (rt << 4) + (lane & 15);
        if (AMODE == 0) aptr[rt] = Abf + ((size_t)m << 9);
        else {
            int mm = m < Mact ? m : (Mact - 1);
            aptr[rt] = Aemb + ((size_t)ridx[mm] << 9);
        }
    }

    f32x4 acc[4][4];
#pragma unroll
    for (int i = 0; i < 4; ++i)
#pragma unroll
        for (int j = 0; j < 4; ++j) acc[i][j] = (f32x4){0.f, 0.f, 0.f, 0.f};

    __syncthreads();

#pragma unroll 4
    for (int ks = 0; ks < 16; ++ks) {
        int koff = (ks << 5) + ((lane >> 4) << 3);
        bf16x8 bq[4];
#pragma unroll
        for (int ct = 0; ct < 4; ++ct) {
            int brow = (wx << 6) + (ct << 4) + (lane & 15);
            int bb = (brow << 10) + (koff << 1); bb ^= (brow & 7) << 4;
            bq[ct] = *(const bf16x8*)(Bs + bb);
        }
#pragma unroll
        for (int rt = 0; rt < 4; ++rt) {
            bf16x8 aq = *(const bf16x8*)(aptr[rt] + koff);
#pragma unroll
            for (int ct = 0; ct < 4; ++ct)
                acc[rt][ct] = __builtin_amdgcn_mfma_f32_16x16x32_bf16(aq, bq[ct], acc[rt][ct], 0, 0, 0);
        }
    }

#pragma unroll
    for (int rt = 0; rt < 4; ++rt) {
        float es4[4] = {0.f, 0.f, 0.f, 0.f};
#pragma unroll
        for (int ct = 0; ct < 4; ++ct) {
            int n = n0 + (wx << 6) + (ct << 4) + (lane & 15);
            bool okn = (n < N);
            float badd = 0.f;
            if (EPI == 3) badd = bias1[n] + bias2[n];
            else if (EPI == 1) badd = okn ? bias1[n] : 0.f;
#pragma unroll
            for (int ri = 0; ri < 4; ++ri) {
                int m = m0 + (wy << 6) + (rt << 4) + ((lane >> 4) << 2) + ri;
                float v = acc[rt][ct][ri] + badd;
                if (EPI == 3) {
                    outf[(size_t)m * N + n] = v;
                } else if (EPI == 0) {
                    if (m < Mact) {
                        int b = rowlist[m] & 255;
                        v += bias1[(size_t)b * NG + n];   // fold gx (incl. biases)
                        outb[(size_t)m * NG + ((n & 511) << 2) + (n >> 9)] = f2bf(v);
                    }
                } else {
                    if (okn && m < Mact) {
                        int r = rowlist[m];
                        outf[(size_t)(r & 255) * PRED_B + (size_t)(r >> 8) * NV + n] = v;
                        es4[ri] += __expf(v);
                    }
                }
            }
        }
        if (EPI == 1) {
#pragma unroll
            for (int ri = 0; ri < 4; ++ri) {
                float s = es4[ri];
                s += __shfl_xor(s, 1); s += __shfl_xor(s, 2);
                s += __shfl_xor(s, 4); s += __shfl_xor(s, 8);
                if ((lane & 15) == 0) {
                    int m = m0 + (wy << 6) + (rt << 4) + ((lane >> 4) << 2) + ri;
                    if (m < Mact) atomicAdd(&rowsum[m], s);
                }
            }
        }
    }
}

// ---------- fused LSTM: W-resident, d-sliced, flag-synced row groups ----------
// 256 blocks x 256 threads (coop). Block b: g = b&15 (row group, rows
// [16g,16g+16)), s = b>>4 (d-slice, h-dims [32s,32s+32), W-slice 128KB in LDS
// for all 30 steps). Per step: full-h 16KB image load -> 32 MFMA/wave ->
// gate LDS exchange -> elementwise -> write h-slice into the shared image
// (hx, pre-swizzled layout) -> release flag. Consumers spin ACQUIRE/AGENT.
__launch_bounds__(256, 1)
__global__ void lstmx_k(const unsigned short* __restrict__ Wimg2,  // [16][128KB]
                        const unsigned short* __restrict__ gallc,  // [n_active][512][4]
                        unsigned short* __restrict__ hx,           // [2][16][16KB image]
                        unsigned short* __restrict__ h_allc,       // [n_active][512]
                        int* __restrict__ flags,                   // [16]
                        const int* __restrict__ cnt,
                        const int* __restrict__ start) {
    __shared__ __align__(16) char Wlds[131072];
    __shared__ __align__(16) char hlds[16384];
    __shared__ float Gs[4 * 16 * 32];
    int tid = threadIdx.x;
    int g = blockIdx.x & 15, s = blockIdx.x >> 4;
    int lane = tid & 63, w = tid >> 6;          // wave w = gate quarter q
    int hi = lane >> 4, lo = lane & 15;
    int q = w;

    // load W slice once (linear copy of pre-swizzled image)
    {
        const char* wsrc = (const char*)Wimg2 + ((size_t)s << 17) + tid * 16;
#pragma unroll 8
        for (int r = 0; r < 32; ++r)
            gl2lds16(wsrc + r * 4096, Wlds + tid * 16 + r * 4096);
    }
    // zero h image
    {
        uint4 z = make_uint4(0u, 0u, 0u, 0u);
        *(uint4*)(hlds + tid * 16) = z;
        *(uint4*)(hlds + 4096 + tid * 16) = z;
        *(uint4*)(hlds + 8192 + tid * 16) = z;
        *(uint4*)(hlds + 12288 + tid * 16) = z;
    }
    asm volatile("s_waitcnt vmcnt(0)" ::: "memory");
    __syncthreads();

    int row = tid >> 4, d0 = tid & 15;          // elementwise ownership
    float creg[2] = {0.f, 0.f};

    for (int t = 0; t < NT; ++t) {
        int cnt_t = cnt[t];
        if (16 * g >= cnt_t) break;
        int nrow = cnt_t - 16 * g; if (nrow > 16) nrow = 16;
        int pos0 = start[t] + 16 * g;

        // issue x-preact loads early (stable data, no ordering needed)
        int rr = row < nrow ? row : nrow - 1;
        const unsigned short* gp = gallc + ((size_t)(pos0 + rr) << 11);
        uint2 gq0 = *(const uint2*)(gp + (s * 32 + d0) * 4);
        uint2 gq1 = *(const uint2*)(gp + (s * 32 + d0 + 16) * 4);

        if (t > 0) {
            int need = 16 * t;
            if (tid == 0) {
                while (__hip_atomic_load(&flags[g], __ATOMIC_RELAXED,
                                         __HIP_MEMORY_SCOPE_AGENT) < need) { }
            }
            __syncthreads();
            (void)__hip_atomic_load(&flags[g], __ATOMIC_ACQUIRE,
                                    __HIP_MEMORY_SCOPE_AGENT);
            const char* hsrc = (const char*)hx +
                ((size_t)(((t - 1) & 1) * 16 + g) << 14) + tid * 16;
#pragma unroll
            for (int r = 0; r < 4; ++r)
                gl2lds16(hsrc + r * 4096, hlds + tid * 16 + r * 4096);
            asm volatile("s_waitcnt vmcnt(0)" ::: "memory");
            __syncthreads();
        }

        // MFMA: 16 rows x 32 cols (this wave's quarter q), K=512
        f32x4 acc[2];
        acc[0] = (f32x4){0.f, 0.f, 0.f, 0.f};
        acc[1] = (f32x4){0.f, 0.f, 0.f, 0.f};
#pragma unroll 4
        for (int kt = 0; kt < 16; ++kt) {
            int ab = (lo << 10) + (((kt << 5) + (hi << 3)) << 1); ab ^= (lo & 7) << 4;
            bf16x8 aq = *(const bf16x8*)(hlds + ab);
#pragma unroll
            for (int ct = 0; ct < 2; ++ct) {
                int R = (q * 2 + ct) * 16 + lo;
                int bb = (R << 10) + ((kt * 64 + hi * 16) ^ ((lo & 7) << 4));
                bf16x8 bq = *(const bf16x8*)(Wlds + bb);
                acc[ct] = __builtin_amdgcn_mfma_f32_16x16x32_bf16(aq, bq, acc[ct], 0, 0, 0);
            }
        }
        // gate exchange: Gs[q][row][d']
#pragma unroll
        for (int ct = 0; ct < 2; ++ct)
#pragma unroll
            for (int ri = 0; ri < 4; ++ri)
                Gs[(q * 16 + hi * 4 + ri) * 32 + ct * 16 + lo] = acc[ct][ri];
        __syncthreads();

        // elementwise: this thread owns (row, d0) and (row, d0+16)
        bool act = row < nrow;
        unsigned short* himg = (unsigned short*)((char*)hx +
            ((size_t)((t & 1) * 16 + g) << 14));
#pragma unroll
        for (int p = 0; p < 2; ++p) {
            int dp = d0 + p * 16;
            int hd = s * 32 + dp;
            const unsigned short* gq = (const unsigned short*)(p ? &gq1 : &gq0);
            float iv = Gs[(0 * 16 + row) * 32 + dp] + bf2f(gq[0]);
            float fv = Gs[(1 * 16 + row) * 32 + dp] + bf2f(gq[1]);
            float gv = Gs[(2 * 16 + row) * 32 + dp] + bf2f(gq[2]);
            float ov = Gs[(3 * 16 + row) * 32 + dp] + bf2f(gq[3]);
            float i_ = 1.f / (1.f + __expf(-iv));
            float f_ = 1.f / (1.f + __expf(-fv));
            float o_ = 1.f / (1.f + __expf(-ov));
            float ea = __expf(-2.f * fabsf(gv));
            float th = (1.f - ea) / (1.f + ea);
            th = (gv < 0.f) ? -th : th;
            float cn = f_ * creg[p] + i_ * th;
            float ec = __expf(-2.f * fabsf(cn));
            float tc = (1.f - ec) / (1.f + ec);
            tc = (cn < 0.f) ? -tc : tc;
            float hn = o_ * tc;
            int hoff = ((row << 10) + (hd << 1)) ^ ((row & 7) << 4);   // image byte
            unsigned short hv;
            if (act) {
                creg[p] = cn;
                hv = f2bf(hn);
                h_allc[(size_t)(pos0 + row) * NH + hd] = hv;
            } else {
                hv = *(const unsigned short*)(hlds + hoff);            // forward h[t-1]
            }
            *(unsigned short*)((char*)himg + hoff) = hv;
        }
        __syncthreads();   // all stores drained (vmcnt0) before release
        if (tid == 0)
            __hip_atomic_fetch_add(&flags[g], 1, __ATOMIC_RELEASE,
                                   __HIP_MEMORY_SCOPE_AGENT);
    }
}

// ---------- final pass: preds = logit - log(rowsum), zero inactive ------------
__global__ void norm_k(float* __restrict__ out, const float* __restrict__ rowsum,
                       const int* __restrict__ cnt, const int* __restrict__ start) {
    int r = blockIdx.x;          // 0..7679, r = t*256+b
    int t = r >> 8, b = r & 255;
    bool act = b < cnt[t];
    float lse = 0.f;
    if (act) lse = logf(rowsum[start[t] + b]);
    float4* row = (float4*)(out + (size_t)b * PRED_B + (size_t)t * NV);
    for (int v4 = threadIdx.x; v4 < NV / 4; v4 += 256) {
        float4 x;
        if (act) {
            x = row[v4];
            x.x -= lse; x.y -= lse; x.z -= lse; x.w -= lse;
        } else {
            x.x = 0.f; x.y = 0.f; x.z = 0.f; x.w = 0.f;
        }
        row[v4] = x;
    }
}

extern "C" void kernel_launch(void* const* d_in, const int* in_sizes, int n_in,
                              void* d_out, int out_size, void* d_ws, size_t ws_size,
                              hipStream_t stream) {
    const float* gimg  = (const float*)d_in[0];
    const int*   w_in  = (const int*)d_in[1];
    const int*   lens  = (const int*)d_in[2];
    const float* emb   = (const float*)d_in[3];
    const float* W_ih  = (const float*)d_in[4];
    const float* W_hh  = (const float*)d_in[5];
    const float* b_ih  = (const float*)d_in[6];
    const float* b_hh  = (const float*)d_in[7];
    const float* W_out = (const float*)d_in[8];
    const float* b_out = (const float*)d_in[9];
    float* out = (float*)d_out;

    char* p = (char*)d_ws;
    auto alloc = [&](size_t bytes) -> char* {
        char* r = p;
        p += (bytes + 255) & ~(size_t)255;
        return r;
    };
    int*   order   = (int*)alloc(NB * 4);
    int*   wsort   = (int*)alloc(NB * ML * 4);
    int*   cnt     = (int*)alloc(NT * 4);
    int*   start   = (int*)alloc((NT + 1) * 4);
    int*   flags   = (int*)alloc(16 * 4);
    int*   rowlist = (int*)alloc((size_t)NT * NB * 4);
    int*   rowwc   = (int*)alloc((size_t)NT * NB * 4);
    float* gx      = (float*)alloc((size_t)NB * NG * 4);
    float* rowsum  = (float*)alloc((size_t)NT * NB * 4);
    unsigned short* g_sb   = (unsigned short*)alloc((size_t)NB * NE * 2);
    unsigned short* hx     = (unsigned short*)alloc((size_t)2 * 16 * 16384);
    unsigned short* h_allc = (unsigned short*)alloc((size_t)NT * NB * NH * 2);
    unsigned short* Wimg2  = (unsigned short*)alloc((size_t)NG * NH * 2);
    unsigned short* Wxl    = (unsigned short*)alloc((size_t)NG * NE * 2);
    unsigned short* Wxb    = (unsigned short*)alloc((size_t)NG * NE * 2);
    unsigned short* Wob    = (unsigned short*)alloc((size_t)NV * NH * 2);
    unsigned short* embb   = (unsigned short*)alloc((size_t)NV * NE * 2);
    unsigned short* gallc  = (unsigned short*)alloc((size_t)NT * NB * NG * 2);
    int* nact = start + NT;   // n_active lives at start[30]

    sort_k<<<1, 256, 0, stream>>>(lens, order, cnt, start, out + OFF_DEC);
    gather_k<<<NB, 256, 0, stream>>>(gimg, w_in, order, g_sb, wsort, out + OFF_TGT);
    rowlist_k<<<NT, 256, 0, stream>>>(wsort, cnt, start, rowlist, rowwc);
    wimg2_k<<<512, 256, 0, stream>>>(W_hh, Wimg2);
    wih_k<<<(NG * NE / 4 + 255) / 256, 256, 0, stream>>>(W_ih, Wxl, 0);
    wih_k<<<(NG * NE / 4 + 255) / 256, 256, 0, stream>>>(W_ih, Wxb, NE);
    f2b_k<<<(NV * NH / 4 + 255) / 256, 256, 0, stream>>>(W_out, Wob, NV * NH / 4);
    f2b_k<<<(NV * NE / 4 + 255) / 256, 256, 0, stream>>>(emb, embb, NV * NE / 4);
    pad_k<<<(NB * NV + 255) / 256, 256, 0, stream>>>(out);
    zero_k<<<(NT * NB + 255) / 256, 256, 0, stream>>>(rowsum, NT * NB);
    zero_k<<<1, 256, 0, stream>>>((float*)flags, 16);

    // gx = g_sb @ Wxl^T + b_ih + b_hh     (256 x 2048, K=512, fp32 out)
    bgemm<0, 3><<<dim3(NG / 128, NB / 128), 256, 0, stream>>>(
        g_sb, nullptr, nullptr, Wxl, NG, nullptr,
        b_ih, b_hh, nullptr, gx, nullptr, nullptr);

    // gallc[pos][d][q] = bf16( emb[rowwc[pos]] @ Wxb^T + gx[b] )   (n_active x 2048)
    bgemm<1, 0><<<dim3(NG / 128, NT * NB / 128), 256, 0, stream>>>(
        nullptr, rowwc, embb, Wxb, NG, nact,
        gx, nullptr, rowlist, nullptr, gallc, nullptr);

    // fused 30-step recurrence: W-resident, flag-synced row groups (cooperative)
    {
        void* cargs[] = { (void*)&Wimg2, (void*)&gallc, (void*)&hx, (void*)&h_allc,
                          (void*)&flags, (void*)&cnt, (void*)&start };
        hipLaunchCooperativeKernel((void*)lstmx_k, dim3(256), dim3(256), cargs, 0, stream);
    }

    // logits = h_allc @ Wob^T + b_out -> preds scatter + rowsum exp-atomics
    bgemm<0, 1><<<dim3((NV + 127) / 128, NT * NB / 128), 256, 0, stream>>>(
        h_allc, nullptr, nullptr, Wob, NV, nact,
        b_out, nullptr, rowlist, out, nullptr, rowsum);

    norm_k<<<NT * NB, 256, 0, stream>>>(out, rowsum, cnt, start);
}

// Round 8
// 634.493 us; speedup vs baseline: 3.6493x; 1.4897x over previous
//
#include <hip/hip_runtime.h>
#include <hip/hip_bf16.h>
#include <math.h>

// Problem constants
#define NB   256      // batch
#define ML   31       // MAX_LEN
#define NT   30       // T = MAX_LEN-1 decode steps
#define NV   10000    // vocab
#define NH   512      // hidden
#define NE   512      // embed
#define NG   2048     // 4*H gates

// Output layout (floats): preds (256,31,10000) | target (256,30) | dec_len (256,)
#define OFF_TGT  (256LL*31LL*10000LL)
#define OFF_DEC  (OFF_TGT + 256LL*30LL)
#define PRED_B   (31LL*10000LL)

typedef __attribute__((ext_vector_type(8))) short bf16x8;
typedef __attribute__((ext_vector_type(4))) float f32x4;

__device__ inline unsigned short f2bf(float f) {
    unsigned int x = __float_as_uint(f);
    unsigned int r = x + 0x7FFFu + ((x >> 16) & 1u);   // RNE
    return (unsigned short)(r >> 16);
}
__device__ inline float bf2f(unsigned short u) {
    return __uint_as_float((unsigned int)u << 16);
}

__device__ inline void gl2lds16(const void* g, void* l) {
    __builtin_amdgcn_global_load_lds(
        (const __attribute__((address_space(1))) unsigned int*)g,
        (__attribute__((address_space(3))) unsigned int*)l, 16, 0, 0);
}

// ---------- sort: stable descending argsort + per-step active counts ----------
__global__ void sort_k(const int* __restrict__ lens, int* __restrict__ order,
                       int* __restrict__ cnt, int* __restrict__ start,
                       float* __restrict__ out_dec) {
    __shared__ int sd[NB];
    int i = threadIdx.x;
    int li = lens[i];
    int r = 0;
    for (int j = 0; j < NB; j++) {
        int lj = lens[j];
        r += (lj > li) || (lj == li && j < i);
    }
    order[r] = i;
    out_dec[r] = (float)(li - 1);
    sd[r] = li - 1;
    __syncthreads();
    if (i < NT) {
        int c = 0;
        for (int b = 0; b < NB; b++) c += (sd[b] > i);
        cnt[i] = c;
    }
    __syncthreads();
    if (i == 0) {
        int s = 0;
        for (int t = 0; t < NT; t++) { start[t] = s; s += cnt[t]; }
        start[NT] = s;                 // n_active
    }
}

// ---------- gather sorted rows (bf16 image), emit target ----------------------
__global__ void gather_k(const float* __restrict__ gimg, const int* __restrict__ w_in,
                         const int* __restrict__ order,
                         unsigned short* __restrict__ g_sb, int* __restrict__ wsort,
                         float* __restrict__ out_tgt) {
    int r = blockIdx.x, tid = threadIdx.x;
    int o = order[r];
    for (int e = tid; e < NE; e += 256)
        g_sb[r * NE + e] = f2bf(gimg[o * NE + e]);
    if (tid < ML) wsort[r * ML + tid] = w_in[o * ML + tid];
    if (tid < NT) out_tgt[r * NT + tid] = (float)w_in[o * ML + tid + 1];
}

// ---------- compact active-row lists ------------------------------------------
__global__ void rowlist_k(const int* __restrict__ wsort, const int* __restrict__ cnt,
                          const int* __restrict__ start,
                          int* __restrict__ rowlist, int* __restrict__ rowwc) {
    int t = blockIdx.x, b = threadIdx.x;
    if (b < cnt[t]) {
        int pos = start[t] + b;
        rowlist[pos] = t * 256 + b;
        rowwc[pos] = wsort[b * ML + t];
    }
}

// ---------- fp32 -> bf16 conversions ------------------------------------------
__global__ void f2b_k(const float* __restrict__ src, unsigned short* __restrict__ dst, int n4) {
    int i = blockIdx.x * 256 + threadIdx.x;
    if (i >= n4) return;
    float4 v = ((const float4*)src)[i];
    ushort4 o;
    o.x = f2bf(v.x); o.y = f2bf(v.y); o.z = f2bf(v.z); o.w = f2bf(v.w);
    ((ushort4*)dst)[i] = o;
}

// dst[j][k] = bf16(W_ih[j][koff+k]), j<2048, k<512
__global__ void wih_k(const float* __restrict__ W_ih, unsigned short* __restrict__ dst, int koff) {
    int gid = blockIdx.x * 256 + threadIdx.x;   // 2048*128 float4 chunks
    int j = gid >> 7, k4 = gid & 127;
    float4 v = *(const float4*)(W_ih + (size_t)j * (2 * NE) + koff + k4 * 4);
    ushort4 o;
    o.x = f2bf(v.x); o.y = f2bf(v.y); o.z = f2bf(v.z); o.w = f2bf(v.w);
    *(ushort4*)(dst + (size_t)j * NE + k4 * 4) = o;
}

// ---------- W_hh -> Wimg2: 16 slices x 128KB, swizzled-LDS-image layout -------
__global__ void wimg2_k(const float* __restrict__ W_hh, unsigned short* __restrict__ Wimg2) {
    int gid = blockIdx.x * 256 + threadIdx.x;   // 131072 = 16s * 128R * 16kt * 4hi
    int hi = gid & 3, kt = (gid >> 2) & 15, R = (gid >> 6) & 127, s = gid >> 13;
    int q = R >> 5, ct = (R >> 4) & 1, lo = R & 15;
    int col = q * 512 + s * 32 + ct * 16 + lo;
    int k = kt * 32 + hi * 8;
    const float* src = W_hh + (size_t)col * NH + k;
    __align__(16) unsigned short o[8];
#pragma unroll
    for (int j = 0; j < 8; ++j) o[j] = f2bf(src[j]);
    int ba = (R << 10) + ((kt * 64 + hi * 16) ^ ((lo & 7) << 4));
    *(uint4*)((char*)Wimg2 + ((size_t)s << 17) + ba) = *(const uint4*)o;
}

// ---------- zero pad column preds[:,30,:] + zero scratch ----------------------
__global__ void pad_k(float* __restrict__ out) {
    int gid = blockIdx.x * 256 + threadIdx.x;
    if (gid < NB * NV) {
        int b = gid / NV, v = gid % NV;
        out[(size_t)b * PRED_B + (size_t)NT * NV + v] = 0.f;
    }
}
__global__ void zero_k(float* __restrict__ p, int n) {
    int i = blockIdx.x * 256 + threadIdx.x;
    if (i < n) p[i] = 0.f;
}

// ---------- bf16 MFMA GEMM, B-panel-in-LDS-once, A direct global --------------
template <int AMODE, int EPI>
__launch_bounds__(256)
__global__ void bgemm(const unsigned short* __restrict__ Abf,
                      const int* __restrict__ ridx,
                      const unsigned short* __restrict__ Aemb,
                      const unsigned short* __restrict__ Bbf,
                      int N,
                      const int* __restrict__ mact_p,
                      const float* __restrict__ bias1,
                      const float* __restrict__ bias2,
                      const int* __restrict__ rowlist,
                      float* __restrict__ outf,
                      unsigned short* __restrict__ outb,
                      float* __restrict__ rowsum) {
    __shared__ __align__(16) char Bs[131072];   // [128][512] bf16, XOR-swizzled
    int Mact = mact_p ? *mact_p : (1 << 30);
    int m0 = blockIdx.y * 128;
    if (m0 >= Mact) return;
    int n0 = blockIdx.x * 128;
    int tid = threadIdx.x;
    int lane = tid & 63, w = tid >> 6;
    int wy = w >> 1, wx = w & 1;

#pragma unroll 4
    for (int p = 0; p < 32; ++p) {
        int row = (tid >> 6) + (p << 2);
        int bn = n0 + row; if (bn > N - 1) bn = N - 1;
        uint4 v = *(const uint4*)(Bbf + ((size_t)bn << 9) + ((tid & 63) << 3));
        int ba = (row << 10) + ((tid & 63) << 4); ba ^= (row & 7) << 4;
        *(uint4*)(Bs + ba) = v;
    }

    const unsigned short* aptr[4];
#pragma unroll
    for (int rt = 0; rt < 4; ++rt) {
        int m = m0 + (wy << 6) + (rt << 4) + (lane & 15);
        if (AMODE == 0) aptr[rt] = Abf + ((size_t)m << 9);
        else {
            int mm = m < Mact ? m : (Mact - 1);
            aptr[rt] = Aemb + ((size_t)ridx[mm] << 9);
        }
    }

    f32x4 acc[4][4];
#pragma unroll
    for (int i = 0; i < 4; ++i)
#pragma unroll
        for (int j = 0; j < 4; ++j) acc[i][j] = (f32x4){0.f, 0.f, 0.f, 0.f};

    __syncthreads();

#pragma unroll 4
    for (int ks = 0; ks < 16; ++ks) {
        int koff = (ks << 5) + ((lane >> 4) << 3);
        bf16x8 bq[4];
#pragma unroll
        for (int ct = 0; ct < 4; ++ct) {
            int brow = (wx << 6) + (ct << 4) + (lane & 15);
            int bb = (brow << 10) + (koff << 1); bb ^= (brow & 7) << 4;
            bq[ct] = *(const bf16x8*)(Bs + bb);
        }
#pragma unroll
        for (int rt = 0; rt < 4; ++rt) {
            bf16x8 aq = *(const bf16x8*)(aptr[rt] + koff);
#pragma unroll
            for (int ct = 0; ct < 4; ++ct)
                acc[rt][ct] = __builtin_amdgcn_mfma_f32_16x16x32_bf16(aq, bq[ct], acc[rt][ct], 0, 0, 0);
        }
    }

#pragma unroll
    for (int rt = 0; rt < 4; ++rt) {
        float es4[4] = {0.f, 0.f, 0.f, 0.f};
#pragma unroll
        for (int ct = 0; ct < 4; ++ct) {
            int n = n0 + (wx << 6) + (ct << 4) + (lane & 15);
            bool okn = (n < N);
            float badd = 0.f;
            if (EPI == 3) badd = bias1[n] + bias2[n];
            else if (EPI == 1) badd = okn ? bias1[n] : 0.f;
#pragma unroll
            for (int ri = 0; ri < 4; ++ri) {
                int m = m0 + (wy << 6) + (rt << 4) + ((lane >> 4) << 2) + ri;
                float v = acc[rt][ct][ri] + badd;
                if (EPI == 3) {
                    outf[(size_t)m * N + n] = v;
                } else if (EPI == 0) {
                    if (m < Mact) {
                        int b = rowlist[m] & 255;
                        v += bias1[(size_t)b * NG + n];   // fold gx (incl. biases)
                        outb[(size_t)m * NG + ((n & 511) << 2) + (n >> 9)] = f2bf(v);
                    }
                } else {
                    if (okn && m < Mact) {
                        int r = rowlist[m];
                        outf[(size_t)(r & 255) * PRED_B + (size_t)(r >> 8) * NV + n] = v;
                        es4[ri] += __expf(v);
                    }
                }
            }
        }
        if (EPI == 1) {
#pragma unroll
            for (int ri = 0; ri < 4; ++ri) {
                float s = es4[ri];
                s += __shfl_xor(s, 1); s += __shfl_xor(s, 2);
                s += __shfl_xor(s, 4); s += __shfl_xor(s, 8);
                if ((lane & 15) == 0) {
                    int m = m0 + (wy << 6) + (rt << 4) + ((lane >> 4) << 2) + ri;
                    if (m < Mact) atomicAdd(&rowsum[m], s);
                }
            }
        }
    }
}

// ---------- fused LSTM: W-resident, d-sliced, single-writer flag slots --------
// 256 blocks x 256 threads (coop). Block b: g = b&15 (rows [16g,16g+16)),
// s = b>>4 (h-dims [32s,32s+32), 128KB W-slice LDS-resident).
// Sync: flags[g*16+s] single-writer slots; plain sc0/sc1 stores & poll loads
// (L3-coherent, no atomics/fences). h image traffic 16B/8B-wide via LDS staging.
__launch_bounds__(256, 1)
__global__ void lstmy_k(const unsigned short* __restrict__ Wimg2,  // [16][128KB]
                        const unsigned short* __restrict__ gallc,  // [n_active][512][4]
                        unsigned short* __restrict__ hx,           // [2][16][16KB image]
                        unsigned short* __restrict__ h_allc,       // [n_active][512]
                        int* __restrict__ flags,                   // [16][16]
                        const int* __restrict__ cnt,
                        const int* __restrict__ start) {
    __shared__ __align__(16) char Wlds[131072];
    __shared__ __align__(16) char hlds[16384];
    __shared__ float Gs[4 * 16 * 32];
    __shared__ __align__(16) unsigned short hstg[16 * 32];   // 1KB slice staging
    int tid = threadIdx.x;
    int g = blockIdx.x & 15, s = blockIdx.x >> 4;
    int lane = tid & 63, w = tid >> 6;          // wave w = gate quarter q
    int hi = lane >> 4, lo = lane & 15;
    int q = w;

    // load W slice once (linear copy of pre-swizzled image)
    {
        const char* wsrc = (const char*)Wimg2 + ((size_t)s << 17) + tid * 16;
#pragma unroll 8
        for (int r = 0; r < 32; ++r)
            gl2lds16(wsrc + r * 4096, Wlds + tid * 16 + r * 4096);
    }
    // zero h image
    {
        uint4 z = make_uint4(0u, 0u, 0u, 0u);
        *(uint4*)(hlds + tid * 16) = z;
        *(uint4*)(hlds + 4096 + tid * 16) = z;
        *(uint4*)(hlds + 8192 + tid * 16) = z;
        *(uint4*)(hlds + 12288 + tid * 16) = z;
    }
    asm volatile("s_waitcnt vmcnt(0)" ::: "memory");
    __syncthreads();

    int row = tid >> 4, d0 = tid & 15;          // elementwise ownership
    float creg[2] = {0.f, 0.f};

    for (int t = 0; t < NT; ++t) {
        int cnt_t = cnt[t];
        if (16 * g >= cnt_t) break;
        int nrow = cnt_t - 16 * g; if (nrow > 16) nrow = 16;
        int pos0 = start[t] + 16 * g;

        // issue x-preact loads early (stable data, plain cached loads)
        int rr = row < nrow ? row : nrow - 1;
        const unsigned short* gp = gallc + ((size_t)(pos0 + rr) << 11);
        uint2 gq0 = *(const uint2*)(gp + (s * 32 + d0) * 4);
        uint2 gq1 = *(const uint2*)(gp + (s * 32 + d0 + 16) * 4);

        if (t > 0) {
            // wait for all 16 producers of group g to have posted step t-1
            if (tid < 16) {
                const int* fp = flags + g * 16 + tid;
                int f;
                do {
                    asm volatile("global_load_dword %0, %1, off sc0 sc1\n\t"
                                 "s_waitcnt vmcnt(0)"
                                 : "=v"(f) : "v"(fp) : "memory");
                } while (f < t);
            }
            __syncthreads();
            // load full-h 16KB image (L3-coherent), stage into LDS
            const char* hsrc = (const char*)hx +
                ((size_t)(((t - 1) & 1) * 16 + g) << 14) + tid * 16;
            uint4 va, vb, vc, vd;
            asm volatile(
                "global_load_dwordx4 %0, %4, off sc0 sc1\n\t"
                "global_load_dwordx4 %1, %5, off sc0 sc1\n\t"
                "global_load_dwordx4 %2, %6, off sc0 sc1\n\t"
                "global_load_dwordx4 %3, %7, off sc0 sc1\n\t"
                "s_waitcnt vmcnt(0)"
                : "=&v"(va), "=&v"(vb), "=&v"(vc), "=&v"(vd)
                : "v"(hsrc), "v"(hsrc + 4096), "v"(hsrc + 8192), "v"(hsrc + 12288)
                : "memory");
            *(uint4*)(hlds + tid * 16) = va;
            *(uint4*)(hlds + 4096 + tid * 16) = vb;
            *(uint4*)(hlds + 8192 + tid * 16) = vc;
            *(uint4*)(hlds + 12288 + tid * 16) = vd;
            __syncthreads();
        }

        // MFMA: 16 rows x 32 cols (this wave's quarter q), K=512
        f32x4 acc[2];
        acc[0] = (f32x4){0.f, 0.f, 0.f, 0.f};
        acc[1] = (f32x4){0.f, 0.f, 0.f, 0.f};
#pragma unroll 4
        for (int kt = 0; kt < 16; ++kt) {
            int ab = (lo << 10) + (((kt << 5) + (hi << 3)) << 1); ab ^= (lo & 7) << 4;
            bf16x8 aq = *(const bf16x8*)(hlds + ab);
#pragma unroll
            for (int ct = 0; ct < 2; ++ct) {
                int R = (q * 2 + ct) * 16 + lo;
                int bb = (R << 10) + ((kt * 64 + hi * 16) ^ ((lo & 7) << 4));
                bf16x8 bq = *(const bf16x8*)(Wlds + bb);
                acc[ct] = __builtin_amdgcn_mfma_f32_16x16x32_bf16(aq, bq, acc[ct], 0, 0, 0);
            }
        }
        // gate exchange: Gs[q][row][d']
#pragma unroll
        for (int ct = 0; ct < 2; ++ct)
#pragma unroll
            for (int ri = 0; ri < 4; ++ri)
                Gs[(q * 16 + hi * 4 + ri) * 32 + ct * 16 + lo] = acc[ct][ri];
        __syncthreads();

        // elementwise: this thread owns (row, d0) and (row, d0+16); stage to LDS
        bool act = row < nrow;
#pragma unroll
        for (int p = 0; p < 2; ++p) {
            int dp = d0 + p * 16;
            int hd = s * 32 + dp;
            const unsigned short* gq = (const unsigned short*)(p ? &gq1 : &gq0);
            float iv = Gs[(0 * 16 + row) * 32 + dp] + bf2f(gq[0]);
            float fv = Gs[(1 * 16 + row) * 32 + dp] + bf2f(gq[1]);
            float gv = Gs[(2 * 16 + row) * 32 + dp] + bf2f(gq[2]);
            float ov = Gs[(3 * 16 + row) * 32 + dp] + bf2f(gq[3]);
            float i_ = 1.f / (1.f + __expf(-iv));
            float f_ = 1.f / (1.f + __expf(-fv));
            float o_ = 1.f / (1.f + __expf(-ov));
            float ea = __expf(-2.f * fabsf(gv));
            float th = (1.f - ea) / (1.f + ea);
            th = (gv < 0.f) ? -th : th;
            float cn = f_ * creg[p] + i_ * th;
            float ec = __expf(-2.f * fabsf(cn));
            float tc = (1.f - ec) / (1.f + ec);
            tc = (cn < 0.f) ? -tc : tc;
            float hn = o_ * tc;
            unsigned short hv;
            if (act) {
                creg[p] = cn;
                hv = f2bf(hn);
            } else {
                int hoff = ((row << 10) + (hd << 1)) ^ ((row & 7) << 4);
                hv = *(const unsigned short*)(hlds + hoff);   // forward h[t-1]
            }
            hstg[row * 32 + dp] = hv;
        }
        __syncthreads();

        // wide store-out: 64 threads x 16B (image sc0/sc1 as 2x8B + h_allc plain)
        if (tid < 64) {
            int crow = tid >> 2, j = tid & 3;
            uint2 v0 = *(const uint2*)(hstg + crow * 32 + j * 8);
            uint2 v1 = *(const uint2*)(hstg + crow * 32 + j * 8 + 4);
            char* himg = (char*)hx + ((size_t)((t & 1) * 16 + g) << 14);
            int dstoff = (crow << 10) + ((((s << 2) + j) ^ (crow & 7)) << 4);
            asm volatile("global_store_dwordx2 %0, %2, off sc0 sc1\n\t"
                         "global_store_dwordx2 %1, %3, off sc0 sc1"
                         :: "v"(himg + dstoff), "v"(himg + dstoff + 8),
                            "v"(v0), "v"(v1) : "memory");
            if (crow < nrow) {
                unsigned short* hap = h_allc + (size_t)(pos0 + crow) * NH + s * 32 + j * 8;
                *(uint2*)hap = v0;
                *(uint2*)(hap + 4) = v1;
            }
        }
        asm volatile("s_waitcnt vmcnt(0)" ::: "memory");
        __syncthreads();   // all lanes' stores drained before post
        if (tid == 0) {
            int fv = t + 1;
            asm volatile("global_store_dword %0, %1, off sc0 sc1"
                         :: "v"(flags + g * 16 + s), "v"(fv) : "memory");
        }
    }
}

// ---------- final pass: preds = logit - log(rowsum), zero inactive ------------
__global__ void norm_k(float* __restrict__ out, const float* __restrict__ rowsum,
                       const int* __restrict__ cnt, const int* __restrict__ start) {
    int r = blockIdx.x;          // 0..7679, r = t*256+b
    int t = r >> 8, b = r & 255;
    bool act = b < cnt[t];
    float lse = 0.f;
    if (act) lse = logf(rowsum[start[t] + b]);
    float4* row = (float4*)(out + (size_t)b * PRED_B + (size_t)t * NV);
    for (int v4 = threadIdx.x; v4 < NV / 4; v4 += 256) {
        float4 x;
        if (act) {
            x = row[v4];
            x.x -= lse; x.y -= lse; x.z -= lse; x.w -= lse;
        } else {
            x.x = 0.f; x.y = 0.f; x.z = 0.f; x.w = 0.f;
        }
        row[v4] = x;
    }
}

extern "C" void kernel_launch(void* const* d_in, const int* in_sizes, int n_in,
                              void* d_out, int out_size, void* d_ws, size_t ws_size,
                              hipStream_t stream) {
    const float* gimg  = (const float*)d_in[0];
    const int*   w_in  = (const int*)d_in[1];
    const int*   lens  = (const int*)d_in[2];
    const float* emb   = (const float*)d_in[3];
    const float* W_ih  = (const float*)d_in[4];
    const float* W_hh  = (const float*)d_in[5];
    const float* b_ih  = (const float*)d_in[6];
    const float* b_hh  = (const float*)d_in[7];
    const float* W_out = (const float*)d_in[8];
    const float* b_out = (const float*)d_in[9];
    float* out = (float*)d_out;

    char* p = (char*)d_ws;
    auto alloc = [&](size_t bytes) -> char* {
        char* r = p;
        p += (bytes + 255) & ~(size_t)255;
        return r;
    };
    int*   order   = (int*)alloc(NB * 4);
    int*   wsort   = (int*)alloc(NB * ML * 4);
    int*   cnt     = (int*)alloc(NT * 4);
    int*   start   = (int*)alloc((NT + 1) * 4);
    int*   flags   = (int*)alloc(256 * 4);
    int*   rowlist = (int*)alloc((size_t)NT * NB * 4);
    int*   rowwc   = (int*)alloc((size_t)NT * NB * 4);
    float* gx      = (float*)alloc((size_t)NB * NG * 4);
    float* rowsum  = (float*)alloc((size_t)NT * NB * 4);
    unsigned short* g_sb   = (unsigned short*)alloc((size_t)NB * NE * 2);
    unsigned short* hx     = (unsigned short*)alloc((size_t)2 * 16 * 16384);
    unsigned short* h_allc = (unsigned short*)alloc((size_t)NT * NB * NH * 2);
    unsigned short* Wimg2  = (unsigned short*)alloc((size_t)NG * NH * 2);
    unsigned short* Wxl    = (unsigned short*)alloc((size_t)NG * NE * 2);
    unsigned short* Wxb    = (unsigned short*)alloc((size_t)NG * NE * 2);
    unsigned short* Wob    = (unsigned short*)alloc((size_t)NV * NH * 2);
    unsigned short* embb   = (unsigned short*)alloc((size_t)NV * NE * 2);
    unsigned short* gallc  = (unsigned short*)alloc((size_t)NT * NB * NG * 2);
    int* nact = start + NT;   // n_active lives at start[30]

    sort_k<<<1, 256, 0, stream>>>(lens, order, cnt, start, out + OFF_DEC);
    gather_k<<<NB, 256, 0, stream>>>(gimg, w_in, order, g_sb, wsort, out + OFF_TGT);
    rowlist_k<<<NT, 256, 0, stream>>>(wsort, cnt, start, rowlist, rowwc);
    wimg2_k<<<512, 256, 0, stream>>>(W_hh, Wimg2);
    wih_k<<<(NG * NE / 4 + 255) / 256, 256, 0, stream>>>(W_ih, Wxl, 0);
    wih_k<<<(NG * NE / 4 + 255) / 256, 256, 0, stream>>>(W_ih, Wxb, NE);
    f2b_k<<<(NV * NH / 4 + 255) / 256, 256, 0, stream>>>(W_out, Wob, NV * NH / 4);
    f2b_k<<<(NV * NE / 4 + 255) / 256, 256, 0, stream>>>(emb, embb, NV * NE / 4);
    pad_k<<<(NB * NV + 255) / 256, 256, 0, stream>>>(out);
    zero_k<<<(NT * NB + 255) / 256, 256, 0, stream>>>(rowsum, NT * NB);
    zero_k<<<1, 256, 0, stream>>>((float*)flags, 256);

    // gx = g_sb @ Wxl^T + b_ih + b_hh     (256 x 2048, K=512, fp32 out)
    bgemm<0, 3><<<dim3(NG / 128, NB / 128), 256, 0, stream>>>(
        g_sb, nullptr, nullptr, Wxl, NG, nullptr,
        b_ih, b_hh, nullptr, gx, nullptr, nullptr);

    // gallc[pos][d][q] = bf16( emb[rowwc[pos]] @ Wxb^T + gx[b] )   (n_active x 2048)
    bgemm<1, 0><<<dim3(NG / 128, NT * NB / 128), 256, 0, stream>>>(
        nullptr, rowwc, embb, Wxb, NG, nact,
        gx, nullptr, rowlist, nullptr, gallc, nullptr);

    // fused 30-step recurrence: W-resident, single-writer flag sync (coop)
    {
        void* cargs[] = { (void*)&Wimg2, (void*)&gallc, (void*)&hx, (void*)&h_allc,
                          (void*)&flags, (void*)&cnt, (void*)&start };
        (void)hipLaunchCooperativeKernel((void*)lstmy_k, dim3(256), dim3(256), cargs, 0, stream);
    }

    // logits = h_allc @ Wob^T + b_out -> preds scatter + rowsum exp-atomics
    bgemm<0, 1><<<dim3((NV + 127) / 128, NT * NB / 128), 256, 0, stream>>>(
        h_allc, nullptr, nullptr, Wob, NV, nact,
        b_out, nullptr, rowlist, out, nullptr, rowsum);

    norm_k<<<NT * NB, 256, 0, stream>>>(out, rowsum, cnt, start);
}

// Round 9
// 493.455 us; speedup vs baseline: 4.6924x; 1.2858x over previous
//
#include <hip/hip_runtime.h>
#include <hip/hip_bf16.h>
#include <math.h>

// Problem constants
#define NB   256      // batch
#define ML   31       // MAX_LEN
#define NT   30       // T = MAX_LEN-1 decode steps
#define NV   10000    // vocab
#define NH   512      // hidden
#define NE   512      // embed
#define NG   2048     // 4*H gates

// Output layout (floats): preds (256,31,10000) | target (256,30) | dec_len (256,)
#define OFF_TGT  (256LL*31LL*10000LL)
#define OFF_DEC  (OFF_TGT + 256LL*30LL)
#define PRED_B   (31LL*10000LL)

typedef __attribute__((ext_vector_type(8))) short bf16x8;
typedef __attribute__((ext_vector_type(4))) float f32x4;

__device__ inline unsigned short f2bf(float f) {
    unsigned int x = __float_as_uint(f);
    unsigned int r = x + 0x7FFFu + ((x >> 16) & 1u);   // RNE
    return (unsigned short)(r >> 16);
}
__device__ inline float bf2f(unsigned short u) {
    return __uint_as_float((unsigned int)u << 16);
}

__device__ inline void gl2lds16(const void* g, void* l) {
    __builtin_amdgcn_global_load_lds(
        (const __attribute__((address_space(1))) unsigned int*)g,
        (__attribute__((address_space(3))) unsigned int*)l, 16, 0, 0);
}

// ---------- sort: stable descending argsort + per-step active counts ----------
__global__ void sort_k(const int* __restrict__ lens, int* __restrict__ order,
                       int* __restrict__ cnt, int* __restrict__ start,
                       float* __restrict__ out_dec) {
    __shared__ int sd[NB];
    int i = threadIdx.x;
    int li = lens[i];
    int r = 0;
    for (int j = 0; j < NB; j++) {
        int lj = lens[j];
        r += (lj > li) || (lj == li && j < i);
    }
    order[r] = i;
    out_dec[r] = (float)(li - 1);
    sd[r] = li - 1;
    __syncthreads();
    if (i < NT) {
        int c = 0;
        for (int b = 0; b < NB; b++) c += (sd[b] > i);
        cnt[i] = c;
    }
    __syncthreads();
    if (i == 0) {
        int s = 0;
        for (int t = 0; t < NT; t++) { start[t] = s; s += cnt[t]; }
        start[NT] = s;                 // n_active
    }
}

// ---------- gather sorted rows (bf16 image), emit target ----------------------
__global__ void gather_k(const float* __restrict__ gimg, const int* __restrict__ w_in,
                         const int* __restrict__ order,
                         unsigned short* __restrict__ g_sb, int* __restrict__ wsort,
                         float* __restrict__ out_tgt) {
    int r = blockIdx.x, tid = threadIdx.x;
    int o = order[r];
    for (int e = tid; e < NE; e += 256)
        g_sb[r * NE + e] = f2bf(gimg[o * NE + e]);
    if (tid < ML) wsort[r * ML + tid] = w_in[o * ML + tid];
    if (tid < NT) out_tgt[r * NT + tid] = (float)w_in[o * ML + tid + 1];
}

// ---------- compact active-row lists ------------------------------------------
__global__ void rowlist_k(const int* __restrict__ wsort, const int* __restrict__ cnt,
                          const int* __restrict__ start,
                          int* __restrict__ rowlist, int* __restrict__ rowwc) {
    int t = blockIdx.x, b = threadIdx.x;
    if (b < cnt[t]) {
        int pos = start[t] + b;
        rowlist[pos] = t * 256 + b;
        rowwc[pos] = wsort[b * ML + t];
    }
}

// ---------- fp32 -> bf16 conversions ------------------------------------------
__global__ void f2b_k(const float* __restrict__ src, unsigned short* __restrict__ dst, int n4) {
    int i = blockIdx.x * 256 + threadIdx.x;
    if (i >= n4) return;
    float4 v = ((const float4*)src)[i];
    ushort4 o;
    o.x = f2bf(v.x); o.y = f2bf(v.y); o.z = f2bf(v.z); o.w = f2bf(v.w);
    ((ushort4*)dst)[i] = o;
}

// dst[j][k] = bf16(W_ih[j][koff+k]), j<2048, k<512
__global__ void wih_k(const float* __restrict__ W_ih, unsigned short* __restrict__ dst, int koff) {
    int gid = blockIdx.x * 256 + threadIdx.x;   // 2048*128 float4 chunks
    int j = gid >> 7, k4 = gid & 127;
    float4 v = *(const float4*)(W_ih + (size_t)j * (2 * NE) + koff + k4 * 4);
    ushort4 o;
    o.x = f2bf(v.x); o.y = f2bf(v.y); o.z = f2bf(v.z); o.w = f2bf(v.w);
    *(ushort4*)(dst + (size_t)j * NE + k4 * 4) = o;
}

// ---------- W_hh -> Wimg2: 16 slices x 128KB, swizzled-LDS-image layout -------
__global__ void wimg2_k(const float* __restrict__ W_hh, unsigned short* __restrict__ Wimg2) {
    int gid = blockIdx.x * 256 + threadIdx.x;   // 131072 = 16s * 128R * 16kt * 4hi
    int hi = gid & 3, kt = (gid >> 2) & 15, R = (gid >> 6) & 127, s = gid >> 13;
    int q = R >> 5, ct = (R >> 4) & 1, lo = R & 15;
    int col = q * 512 + s * 32 + ct * 16 + lo;
    int k = kt * 32 + hi * 8;
    const float* src = W_hh + (size_t)col * NH + k;
    __align__(16) unsigned short o[8];
#pragma unroll
    for (int j = 0; j < 8; ++j) o[j] = f2bf(src[j]);
    int ba = (R << 10) + ((kt * 64 + hi * 16) ^ ((lo & 7) << 4));
    *(uint4*)((char*)Wimg2 + ((size_t)s << 17) + ba) = *(const uint4*)o;
}

// ---------- zero pad column preds[:,30,:] + zero scratch ----------------------
__global__ void pad_k(float* __restrict__ out) {
    int gid = blockIdx.x * 256 + threadIdx.x;
    if (gid < NB * NV) {
        int b = gid / NV, v = gid % NV;
        out[(size_t)b * PRED_B + (size_t)NT * NV + v] = 0.f;
    }
}
__global__ void zero_k(float* __restrict__ p, int n) {
    int i = blockIdx.x * 256 + threadIdx.x;
    if (i < n) p[i] = 0.f;
}

// ---------- bf16 MFMA GEMM, B-panel-in-LDS-once, A direct global --------------
// (used for the two small preamble GEMMs: EPI 0 gallc producer, EPI 3 gx)
template <int AMODE, int EPI>
__launch_bounds__(256)
__global__ void bgemm(const unsigned short* __restrict__ Abf,
                      const int* __restrict__ ridx,
                      const unsigned short* __restrict__ Aemb,
                      const unsigned short* __restrict__ Bbf,
                      int N,
                      const int* __restrict__ mact_p,
                      const float* __restrict__ bias1,
                      const float* __restrict__ bias2,
                      const int* __restrict__ rowlist,
                      float* __restrict__ outf,
                      unsigned short* __restrict__ outb,
                      float* __restrict__ rowsum) {
    __shared__ __align__(16) char Bs[131072];   // [128][512] bf16, XOR-swizzled
    int Mact = mact_p ? *mact_p : (1 << 30);
    int m0 = blockIdx.y * 128;
    if (m0 >= Mact) return;
    int n0 = blockIdx.x * 128;
    int tid = threadIdx.x;
    int lane = tid & 63, w = tid >> 6;
    int wy = w >> 1, wx = w & 1;

#pragma unroll 4
    for (int p = 0; p < 32; ++p) {
        int row = (tid >> 6) + (p << 2);
        int bn = n0 + row; if (bn > N - 1) bn = N - 1;
        uint4 v = *(const uint4*)(Bbf + ((size_t)bn << 9) + ((tid & 63) << 3));
        int ba = (row << 10) + ((tid & 63) << 4); ba ^= (row & 7) << 4;
        *(uint4*)(Bs + ba) = v;
    }

    const unsigned short* aptr[4];
#pragma unroll
    for (int rt = 0; rt < 4; ++rt) {
        int m = m0 + (wy << 6) + (rt << 4) + (lane & 15);
        if (AMODE == 0) aptr[rt] = Abf + ((size_t)m << 9);
        else {
            int mm = m < Mact ? m : (Mact - 1);
            aptr[rt] = Aemb + ((size_t)ridx[mm] << 9);
        }
    }

    f32x4 acc[4][4];
#pragma unroll
    for (int i = 0; i < 4; ++i)
#pragma unroll
        for (int j = 0; j < 4; ++j) acc[i][j] = (f32x4){0.f, 0.f, 0.f, 0.f};

    __syncthreads();

#pragma unroll 4
    for (int ks = 0; ks < 16; ++ks) {
        int koff = (ks << 5) + ((lane >> 4) << 3);
        bf16x8 bq[4];
#pragma unroll
        for (int ct = 0; ct < 4; ++ct) {
            int brow = (wx << 6) + (ct << 4) + (lane & 15);
            int bb = (brow << 10) + (koff << 1); bb ^= (brow & 7) << 4;
            bq[ct] = *(const bf16x8*)(Bs + bb);
        }
#pragma unroll
        for (int rt = 0; rt < 4; ++rt) {
            bf16x8 aq = *(const bf16x8*)(aptr[rt] + koff);
#pragma unroll
            for (int ct = 0; ct < 4; ++ct)
                acc[rt][ct] = __builtin_amdgcn_mfma_f32_16x16x32_bf16(aq, bq[ct], acc[rt][ct], 0, 0, 0);
        }
    }

#pragma unroll
    for (int rt = 0; rt < 4; ++rt) {
#pragma unroll
        for (int ct = 0; ct < 4; ++ct) {
            int n = n0 + (wx << 6) + (ct << 4) + (lane & 15);
            float badd = 0.f;
            if (EPI == 3) badd = bias1[n] + bias2[n];
#pragma unroll
            for (int ri = 0; ri < 4; ++ri) {
                int m = m0 + (wy << 6) + (rt << 4) + ((lane >> 4) << 2) + ri;
                float v = acc[rt][ct][ri] + badd;
                if (EPI == 3) {
                    outf[(size_t)m * N + n] = v;
                } else {
                    if (m < Mact) {
                        int b = rowlist[m] & 255;
                        v += bias1[(size_t)b * NG + n];   // fold gx (incl. biases)
                        outb[(size_t)m * NG + ((n & 511) << 2) + (n >> 9)] = f2bf(v);
                    }
                }
            }
        }
    }
}

// ---------- output GEMM: m97-style double-buffered global_load_lds pipeline ---
// C(Mact x 10000) = h_allc @ Wob^T + b_out -> preds scatter + rowsum exp-atomics.
// 128x128 tile, BK=64, 4 waves (2x2), A+B staged via global_load_lds width=16,
// double-buffered (64KB LDS -> 2 blocks/CU). Pre-swizzled source (chunk
// ch^(row&7)) gives conflict-free swizzled ds_read with linear DMA dest.
__launch_bounds__(256)
__global__ void ogemm(const unsigned short* __restrict__ Abf,   // [M][512]
                      const unsigned short* __restrict__ Bbf,   // [10000][512]
                      const int* __restrict__ mact_p,
                      const float* __restrict__ bout,
                      const int* __restrict__ rowlist,
                      float* __restrict__ outf,
                      float* __restrict__ rowsum) {
    __shared__ __align__(16) char lds[65536];   // A[2][16K] | B[2][16K]
    int Mact = *mact_p;
    int m0 = blockIdx.y * 128;
    if (m0 >= Mact) return;
    int n0 = blockIdx.x * 128;
    int tid = threadIdx.x;
    int lane = tid & 63, w = tid >> 6;
    int wy = w >> 1, wx = w & 1;
    int hi = lane >> 4, lo = lane & 15;

    // precompute staging source addresses' row/chunk geometry
    auto stage = [&](int kt, int buf) {
#pragma unroll
        for (int i = 0; i < 4; ++i) {
            int p = (i << 8) + tid;
            int row = p >> 3, sc = (p & 7) ^ (row & 7);
            int ma = m0 + row; if (ma > Mact - 1) ma = Mact - 1;
            gl2lds16((const char*)Abf + ((size_t)ma << 10) + (kt << 7) + (sc << 4),
                     lds + (buf << 14) + (p << 4));
        }
#pragma unroll
        for (int i = 0; i < 4; ++i) {
            int p = (i << 8) + tid;
            int row = p >> 3, sc = (p & 7) ^ (row & 7);
            int nb = n0 + row; if (nb > NV - 1) nb = NV - 1;
            gl2lds16((const char*)Bbf + ((size_t)nb << 10) + (kt << 7) + (sc << 4),
                     lds + 32768 + (buf << 14) + (p << 4));
        }
    };

    f32x4 acc[4][4];
#pragma unroll
    for (int i = 0; i < 4; ++i)
#pragma unroll
        for (int j = 0; j < 4; ++j) acc[i][j] = (f32x4){0.f, 0.f, 0.f, 0.f};

    stage(0, 0);
    __syncthreads();

    for (int kt = 0; kt < 8; ++kt) {
        int buf = kt & 1;
        if (kt < 7) stage(kt + 1, buf ^ 1);
#pragma unroll
        for (int kc = 0; kc < 2; ++kc) {
            bf16x8 aq[4], bq[4];
#pragma unroll
            for (int rt = 0; rt < 4; ++rt) {
                int ra = (wy << 6) + (rt << 4) + lo;
                int cha = ((kc << 2) + hi) ^ (ra & 7);
                aq[rt] = *(const bf16x8*)(lds + (buf << 14) + (ra << 7) + (cha << 4));
                int cb = (wx << 6) + (rt << 4) + lo;
                int chb = ((kc << 2) + hi) ^ (cb & 7);
                bq[rt] = *(const bf16x8*)(lds + 32768 + (buf << 14) + (cb << 7) + (chb << 4));
            }
#pragma unroll
            for (int rt = 0; rt < 4; ++rt)
#pragma unroll
                for (int ct = 0; ct < 4; ++ct)
                    acc[rt][ct] = __builtin_amdgcn_mfma_f32_16x16x32_bf16(aq[rt], bq[ct], acc[rt][ct], 0, 0, 0);
        }
        __syncthreads();
    }

    // epilogue: preds scatter + per-row sum(exp) atomics
#pragma unroll
    for (int rt = 0; rt < 4; ++rt) {
        float es4[4] = {0.f, 0.f, 0.f, 0.f};
#pragma unroll
        for (int ct = 0; ct < 4; ++ct) {
            int n = n0 + (wx << 6) + (ct << 4) + lo;
            bool okn = (n < NV);
            float bo = okn ? bout[n] : 0.f;
#pragma unroll
            for (int ri = 0; ri < 4; ++ri) {
                int m = m0 + (wy << 6) + (rt << 4) + (hi << 2) + ri;
                float v = acc[rt][ct][ri] + bo;
                if (okn && m < Mact) {
                    int r = rowlist[m];
                    outf[(size_t)(r & 255) * PRED_B + (size_t)(r >> 8) * NV + n] = v;
                    es4[ri] += __expf(v);
                }
            }
        }
#pragma unroll
        for (int ri = 0; ri < 4; ++ri) {
            float s = es4[ri];
            s += __shfl_xor(s, 1); s += __shfl_xor(s, 2);
            s += __shfl_xor(s, 4); s += __shfl_xor(s, 8);
            if (lo == 0) {
                int m = m0 + (wy << 6) + (rt << 4) + (hi << 2) + ri;
                if (m < Mact) atomicAdd(&rowsum[m], s);
            }
        }
    }
}

// ---------- fused LSTM: W-resident, d-sliced, single-writer flag slots --------
// 256 blocks x 256 threads (coop). Block b: g = b&15 (rows [16g,16g+16)),
// s = b>>4 (h-dims [32s,32s+32), 128KB W-slice LDS-resident).
// Sync: flags[g*16+s] single-writer slots; plain sc0/sc1 stores & poll loads
// (L3-coherent, no atomics/fences). h image traffic 16B/8B-wide via LDS staging.
__launch_bounds__(256, 1)
__global__ void lstmy_k(const unsigned short* __restrict__ Wimg2,  // [16][128KB]
                        const unsigned short* __restrict__ gallc,  // [n_active][512][4]
                        unsigned short* __restrict__ hx,           // [2][16][16KB image]
                        unsigned short* __restrict__ h_allc,       // [n_active][512]
                        int* __restrict__ flags,                   // [16][16]
                        const int* __restrict__ cnt,
                        const int* __restrict__ start) {
    __shared__ __align__(16) char Wlds[131072];
    __shared__ __align__(16) char hlds[16384];
    __shared__ float Gs[4 * 16 * 32];
    __shared__ __align__(16) unsigned short hstg[16 * 32];   // 1KB slice staging
    int tid = threadIdx.x;
    int g = blockIdx.x & 15, s = blockIdx.x >> 4;
    int lane = tid & 63, w = tid >> 6;          // wave w = gate quarter q
    int hi = lane >> 4, lo = lane & 15;
    int q = w;

    // load W slice once (linear copy of pre-swizzled image)
    {
        const char* wsrc = (const char*)Wimg2 + ((size_t)s << 17) + tid * 16;
#pragma unroll 8
        for (int r = 0; r < 32; ++r)
            gl2lds16(wsrc + r * 4096, Wlds + tid * 16 + r * 4096);
    }
    // zero h image
    {
        uint4 z = make_uint4(0u, 0u, 0u, 0u);
        *(uint4*)(hlds + tid * 16) = z;
        *(uint4*)(hlds + 4096 + tid * 16) = z;
        *(uint4*)(hlds + 8192 + tid * 16) = z;
        *(uint4*)(hlds + 12288 + tid * 16) = z;
    }
    asm volatile("s_waitcnt vmcnt(0)" ::: "memory");
    __syncthreads();

    int row = tid >> 4, d0 = tid & 15;          // elementwise ownership
    float creg[2] = {0.f, 0.f};

    for (int t = 0; t < NT; ++t) {
        int cnt_t = cnt[t];
        if (16 * g >= cnt_t) break;
        int nrow = cnt_t - 16 * g; if (nrow > 16) nrow = 16;
        int pos0 = start[t] + 16 * g;

        // issue x-preact loads early (stable data, plain cached loads)
        int rr = row < nrow ? row : nrow - 1;
        const unsigned short* gp = gallc + ((size_t)(pos0 + rr) << 11);
        uint2 gq0 = *(const uint2*)(gp + (s * 32 + d0) * 4);
        uint2 gq1 = *(const uint2*)(gp + (s * 32 + d0 + 16) * 4);

        if (t > 0) {
            // wait for all 16 producers of group g to have posted step t-1
            if (tid < 16) {
                const int* fp = flags + g * 16 + tid;
                int f;
                do {
                    asm volatile("global_load_dword %0, %1, off sc0 sc1\n\t"
                                 "s_waitcnt vmcnt(0)"
                                 : "=v"(f) : "v"(fp) : "memory");
                } while (f < t);
            }
            __syncthreads();
            // load full-h 16KB image (L3-coherent), stage into LDS
            const char* hsrc = (const char*)hx +
                ((size_t)(((t - 1) & 1) * 16 + g) << 14) + tid * 16;
            uint4 va, vb, vc, vd;
            asm volatile(
                "global_load_dwordx4 %0, %4, off sc0 sc1\n\t"
                "global_load_dwordx4 %1, %5, off sc0 sc1\n\t"
                "global_load_dwordx4 %2, %6, off sc0 sc1\n\t"
                "global_load_dwordx4 %3, %7, off sc0 sc1\n\t"
                "s_waitcnt vmcnt(0)"
                : "=&v"(va), "=&v"(vb), "=&v"(vc), "=&v"(vd)
                : "v"(hsrc), "v"(hsrc + 4096), "v"(hsrc + 8192), "v"(hsrc + 12288)
                : "memory");
            *(uint4*)(hlds + tid * 16) = va;
            *(uint4*)(hlds + 4096 + tid * 16) = vb;
            *(uint4*)(hlds + 8192 + tid * 16) = vc;
            *(uint4*)(hlds + 12288 + tid * 16) = vd;
            __syncthreads();
        }

        // MFMA: 16 rows x 32 cols (this wave's quarter q), K=512
        f32x4 acc[2];
        acc[0] = (f32x4){0.f, 0.f, 0.f, 0.f};
        acc[1] = (f32x4){0.f, 0.f, 0.f, 0.f};
#pragma unroll 4
        for (int kt = 0; kt < 16; ++kt) {
            int ab = (lo << 10) + (((kt << 5) + (hi << 3)) << 1); ab ^= (lo & 7) << 4;
            bf16x8 aq = *(const bf16x8*)(hlds + ab);
#pragma unroll
            for (int ct = 0; ct < 2; ++ct) {
                int R = (q * 2 + ct) * 16 + lo;
                int bb = (R << 10) + ((kt * 64 + hi * 16) ^ ((lo & 7) << 4));
                bf16x8 bq = *(const bf16x8*)(Wlds + bb);
                acc[ct] = __builtin_amdgcn_mfma_f32_16x16x32_bf16(aq, bq, acc[ct], 0, 0, 0);
            }
        }
        // gate exchange: Gs[q][row][d']
#pragma unroll
        for (int ct = 0; ct < 2; ++ct)
#pragma unroll
            for (int ri = 0; ri < 4; ++ri)
                Gs[(q * 16 + hi * 4 + ri) * 32 + ct * 16 + lo] = acc[ct][ri];
        __syncthreads();

        // elementwise: this thread owns (row, d0) and (row, d0+16); stage to LDS
        bool act = row < nrow;
#pragma unroll
        for (int p = 0; p < 2; ++p) {
            int dp = d0 + p * 16;
            int hd = s * 32 + dp;
            const unsigned short* gq = (const unsigned short*)(p ? &gq1 : &gq0);
            float iv = Gs[(0 * 16 + row) * 32 + dp] + bf2f(gq[0]);
            float fv = Gs[(1 * 16 + row) * 32 + dp] + bf2f(gq[1]);
            float gv = Gs[(2 * 16 + row) * 32 + dp] + bf2f(gq[2]);
            float ov = Gs[(3 * 16 + row) * 32 + dp] + bf2f(gq[3]);
            float i_ = 1.f / (1.f + __expf(-iv));
            float f_ = 1.f / (1.f + __expf(-fv));
            float o_ = 1.f / (1.f + __expf(-ov));
            float ea = __expf(-2.f * fabsf(gv));
            float th = (1.f - ea) / (1.f + ea);
            th = (gv < 0.f) ? -th : th;
            float cn = f_ * creg[p] + i_ * th;
            float ec = __expf(-2.f * fabsf(cn));
            float tc = (1.f - ec) / (1.f + ec);
            tc = (cn < 0.f) ? -tc : tc;
            float hn = o_ * tc;
            unsigned short hv;
            if (act) {
                creg[p] = cn;
                hv = f2bf(hn);
            } else {
                int hoff = ((row << 10) + (hd << 1)) ^ ((row & 7) << 4);
                hv = *(const unsigned short*)(hlds + hoff);   // forward h[t-1]
            }
            hstg[row * 32 + dp] = hv;
        }
        __syncthreads();

        // wide store-out: 64 threads x 16B (image sc0/sc1 as 2x8B + h_allc plain)
        if (tid < 64) {
            int crow = tid >> 2, j = tid & 3;
            uint2 v0 = *(const uint2*)(hstg + crow * 32 + j * 8);
            uint2 v1 = *(const uint2*)(hstg + crow * 32 + j * 8 + 4);
            char* himg = (char*)hx + ((size_t)((t & 1) * 16 + g) << 14);
            int dstoff = (crow << 10) + ((((s << 2) + j) ^ (crow & 7)) << 4);
            asm volatile("global_store_dwordx2 %0, %2, off sc0 sc1\n\t"
                         "global_store_dwordx2 %1, %3, off sc0 sc1"
                         :: "v"(himg + dstoff), "v"(himg + dstoff + 8),
                            "v"(v0), "v"(v1) : "memory");
            if (crow < nrow) {
                unsigned short* hap = h_allc + (size_t)(pos0 + crow) * NH + s * 32 + j * 8;
                *(uint2*)hap = v0;
                *(uint2*)(hap + 4) = v1;
            }
        }
        asm volatile("s_waitcnt vmcnt(0)" ::: "memory");
        __syncthreads();   // all lanes' stores drained before post
        if (tid == 0) {
            int fv = t + 1;
            asm volatile("global_store_dword %0, %1, off sc0 sc1"
                         :: "v"(flags + g * 16 + s), "v"(fv) : "memory");
        }
    }
}

// ---------- final pass: preds = logit - log(rowsum), zero inactive ------------
__global__ void norm_k(float* __restrict__ out, const float* __restrict__ rowsum,
                       const int* __restrict__ cnt, const int* __restrict__ start) {
    int r = blockIdx.x;          // 0..7679, r = t*256+b
    int t = r >> 8, b = r & 255;
    bool act = b < cnt[t];
    float lse = 0.f;
    if (act) lse = logf(rowsum[start[t] + b]);
    float4* row = (float4*)(out + (size_t)b * PRED_B + (size_t)t * NV);
    for (int v4 = threadIdx.x; v4 < NV / 4; v4 += 256) {
        float4 x;
        if (act) {
            x = row[v4];
            x.x -= lse; x.y -= lse; x.z -= lse; x.w -= lse;
        } else {
            x.x = 0.f; x.y = 0.f; x.z = 0.f; x.w = 0.f;
        }
        row[v4] = x;
    }
}

extern "C" void kernel_launch(void* const* d_in, const int* in_sizes, int n_in,
                              void* d_out, int out_size, void* d_ws, size_t ws_size,
                              hipStream_t stream) {
    const float* gimg  = (const float*)d_in[0];
    const int*   w_in  = (const int*)d_in[1];
    const int*   lens  = (const int*)d_in[2];
    const float* emb   = (const float*)d_in[3];
    const float* W_ih  = (const float*)d_in[4];
    const float* W_hh  = (const float*)d_in[5];
    const float* b_ih  = (const float*)d_in[6];
    const float* b_hh  = (const float*)d_in[7];
    const float* W_out = (const float*)d_in[8];
    const float* b_out = (const float*)d_in[9];
    float* out = (float*)d_out;

    char* p = (char*)d_ws;
    auto alloc = [&](size_t bytes) -> char* {
        char* r = p;
        p += (bytes + 255) & ~(size_t)255;
        return r;
    };
    int*   order   = (int*)alloc(NB * 4);
    int*   wsort   = (int*)alloc(NB * ML * 4);
    int*   cnt     = (int*)alloc(NT * 4);
    int*   start   = (int*)alloc((NT + 1) * 4);
    int*   flags   = (int*)alloc(256 * 4);
    int*   rowlist = (int*)alloc((size_t)NT * NB * 4);
    int*   rowwc   = (int*)alloc((size_t)NT * NB * 4);
    float* gx      = (float*)alloc((size_t)NB * NG * 4);
    float* rowsum  = (float*)alloc((size_t)NT * NB * 4);
    unsigned short* g_sb   = (unsigned short*)alloc((size_t)NB * NE * 2);
    unsigned short* hx     = (unsigned short*)alloc((size_t)2 * 16 * 16384);
    unsigned short* h_allc = (unsigned short*)alloc((size_t)NT * NB * NH * 2);
    unsigned short* Wimg2  = (unsigned short*)alloc((size_t)NG * NH * 2);
    unsigned short* Wxl    = (unsigned short*)alloc((size_t)NG * NE * 2);
    unsigned short* Wxb    = (unsigned short*)alloc((size_t)NG * NE * 2);
    unsigned short* Wob    = (unsigned short*)alloc((size_t)NV * NH * 2);
    unsigned short* embb   = (unsigned short*)alloc((size_t)NV * NE * 2);
    unsigned short* gallc  = (unsigned short*)alloc((size_t)NT * NB * NG * 2);
    int* nact = start + NT;   // n_active lives at start[30]

    sort_k<<<1, 256, 0, stream>>>(lens, order, cnt, start, out + OFF_DEC);
    gather_k<<<NB, 256, 0, stream>>>(gimg, w_in, order, g_sb, wsort, out + OFF_TGT);
    rowlist_k<<<NT, 256, 0, stream>>>(wsort, cnt, start, rowlist, rowwc);
    wimg2_k<<<512, 256, 0, stream>>>(W_hh, Wimg2);
    wih_k<<<(NG * NE / 4 + 255) / 256, 256, 0, stream>>>(W_ih, Wxl, 0);
    wih_k<<<(NG * NE / 4 + 255) / 256, 256, 0, stream>>>(W_ih, Wxb, NE);
    f2b_k<<<(NV * NH / 4 + 255) / 256, 256, 0, stream>>>(W_out, Wob, NV * NH / 4);
    f2b_k<<<(NV * NE / 4 + 255) / 256, 256, 0, stream>>>(emb, embb, NV * NE / 4);
    pad_k<<<(NB * NV + 255) / 256, 256, 0, stream>>>(out);
    zero_k<<<(NT * NB + 255) / 256, 256, 0, stream>>>(rowsum, NT * NB);
    zero_k<<<1, 256, 0, stream>>>((float*)flags, 256);

    // gx = g_sb @ Wxl^T + b_ih + b_hh     (256 x 2048, K=512, fp32 out)
    bgemm<0, 3><<<dim3(NG / 128, NB / 128), 256, 0, stream>>>(
        g_sb, nullptr, nullptr, Wxl, NG, nullptr,
        b_ih, b_hh, nullptr, gx, nullptr, nullptr);

    // gallc[pos][d][q] = bf16( emb[rowwc[pos]] @ Wxb^T + gx[b] )   (n_active x 2048)
    bgemm<1, 0><<<dim3(NG / 128, NT * NB / 128), 256, 0, stream>>>(
        nullptr, rowwc, embb, Wxb, NG, nact,
        gx, nullptr, rowlist, nullptr, gallc, nullptr);

    // fused 30-step recurrence: W-resident, single-writer flag sync (coop)
    {
        void* cargs[] = { (void*)&Wimg2, (void*)&gallc, (void*)&hx, (void*)&h_allc,
                          (void*)&flags, (void*)&cnt, (void*)&start };
        (void)hipLaunchCooperativeKernel((void*)lstmy_k, dim3(256), dim3(256), cargs, 0, stream);
    }

    // logits = h_allc @ Wob^T + b_out -> preds scatter + rowsum exp-atomics
    // m97-style pipelined GEMM
    ogemm<<<dim3((NV + 127) / 128, NT * NB / 128), 256, 0, stream>>>(
        h_allc, Wob, nact, b_out, rowlist, out, rowsum);

    norm_k<<<NT * NB, 256, 0, stream>>>(out, rowsum, cnt, start);
}

// Round 10
// 435.024 us; speedup vs baseline: 5.3227x; 1.1343x over previous
//
#include <hip/hip_runtime.h>
#include <hip/hip_bf16.h>
#include <math.h>

// Problem constants
#define NB   256      // batch
#define ML   31       // MAX_LEN
#define NT   30       // T = MAX_LEN-1 decode steps
#define NV   10000    // vocab
#define NH   512      // hidden
#define NE   512      // embed
#define NG   2048     // 4*H gates

// Output layout (floats): preds (256,31,10000) | target (256,30) | dec_len (256,)
#define OFF_TGT  (256LL*31LL*10000LL)
#define OFF_DEC  (OFF_TGT + 256LL*30LL)
#define PRED_B   (31LL*10000LL)

typedef __attribute__((ext_vector_type(8))) short bf16x8;
typedef __attribute__((ext_vector_type(4))) float f32x4;

__device__ inline unsigned short f2bf(float f) {
    unsigned int x = __float_as_uint(f);
    unsigned int r = x + 0x7FFFu + ((x >> 16) & 1u);   // RNE
    return (unsigned short)(r >> 16);
}
__device__ inline float bf2f(unsigned short u) {
    return __uint_as_float((unsigned int)u << 16);
}

__device__ inline void gl2lds16(const void* g, void* l) {
    __builtin_amdgcn_global_load_lds(
        (const __attribute__((address_space(1))) unsigned int*)g,
        (__attribute__((address_space(3))) unsigned int*)l, 16, 0, 0);
}

// ---------- sort: stable descending argsort + counts + zero flags -------------
__global__ void sort_k(const int* __restrict__ lens, int* __restrict__ order,
                       int* __restrict__ cnt, int* __restrict__ start,
                       int* __restrict__ flags, float* __restrict__ out_dec) {
    __shared__ int sd[NB];
    int i = threadIdx.x;
    flags[i] = 0;
    int li = lens[i];
    int r = 0;
    for (int j = 0; j < NB; j++) {
        int lj = lens[j];
        r += (lj > li) || (lj == li && j < i);
    }
    order[r] = i;
    out_dec[r] = (float)(li - 1);
    sd[r] = li - 1;
    __syncthreads();
    if (i < NT) {
        int c = 0;
        for (int b = 0; b < NB; b++) c += (sd[b] > i);
        cnt[i] = c;
    }
    __syncthreads();
    if (i == 0) {
        int s = 0;
        for (int t = 0; t < NT; t++) { start[t] = s; s += cnt[t]; }
        start[NT] = s;                 // n_active
    }
}

// ---------- gather sorted rows (bf16 image), emit target ----------------------
__global__ void gather_k(const float* __restrict__ gimg, const int* __restrict__ w_in,
                         const int* __restrict__ order,
                         unsigned short* __restrict__ g_sb, int* __restrict__ wsort,
                         float* __restrict__ out_tgt) {
    int r = blockIdx.x, tid = threadIdx.x;
    int o = order[r];
    for (int e = tid; e < NE; e += 256)
        g_sb[r * NE + e] = f2bf(gimg[o * NE + e]);
    if (tid < ML) wsort[r * ML + tid] = w_in[o * ML + tid];
    if (tid < NT) out_tgt[r * NT + tid] = (float)w_in[o * ML + tid + 1];
}

// ---------- compact active-row lists + zero rowsum ----------------------------
__global__ void rowlist_k(const int* __restrict__ wsort, const int* __restrict__ cnt,
                          const int* __restrict__ start,
                          int* __restrict__ rowlist, int* __restrict__ rowwc,
                          float* __restrict__ rowsum) {
    int t = blockIdx.x, b = threadIdx.x;
    rowsum[t * 256 + b] = 0.f;
    if (b < cnt[t]) {
        int pos = start[t] + b;
        rowlist[pos] = t * 256 + b;
        rowwc[pos] = wsort[b * ML + t];
    }
}

// ---------- fused preamble conversions ----------------------------------------
// blocks [0,1024): Wxl = bf16(W_ih[:, :512])
// blocks [1024,2048): Wxb = bf16(W_ih[:, 512:])
// blocks [2048,7048): Wob = bf16(W_out)
// blocks [7048,12048): embb = bf16(emb)
// blocks [12048,12560): Wimg2 (swizzled W_hh image, 16 slices x 128KB)
__global__ void prep_k(const float* __restrict__ W_ih, const float* __restrict__ W_hh,
                       const float* __restrict__ W_out, const float* __restrict__ emb,
                       unsigned short* __restrict__ Wxl, unsigned short* __restrict__ Wxb,
                       unsigned short* __restrict__ Wob, unsigned short* __restrict__ embb,
                       unsigned short* __restrict__ Wimg2) {
    int bid = blockIdx.x, tid = threadIdx.x;
    if (bid < 2048) {
        int koff = (bid < 1024) ? 0 : NE;
        unsigned short* dst = (bid < 1024) ? Wxl : Wxb;
        int gid = ((bid & 1023) << 8) + tid;        // 2048*128 float4 chunks
        int j = gid >> 7, k4 = gid & 127;
        float4 v = *(const float4*)(W_ih + (size_t)j * (2 * NE) + koff + k4 * 4);
        ushort4 o;
        o.x = f2bf(v.x); o.y = f2bf(v.y); o.z = f2bf(v.z); o.w = f2bf(v.w);
        *(ushort4*)(dst + (size_t)j * NE + k4 * 4) = o;
    } else if (bid < 12048) {
        const float* src = (bid < 7048) ? W_out : emb;
        unsigned short* dst = (bid < 7048) ? Wob : embb;
        int gid = ((bid < 7048 ? bid - 2048 : bid - 7048) << 8) + tid;  // < 1,280,000
        float4 v = ((const float4*)src)[gid];
        ushort4 o;
        o.x = f2bf(v.x); o.y = f2bf(v.y); o.z = f2bf(v.z); o.w = f2bf(v.w);
        ((ushort4*)dst)[gid] = o;
    } else {
        int gid = ((bid - 12048) << 8) + tid;       // 131072 = 16s*128R*16kt*4hi
        int hi = gid & 3, kt = (gid >> 2) & 15, R = (gid >> 6) & 127, s = gid >> 13;
        int q = R >> 5, ct = (R >> 4) & 1, lo = R & 15;
        int col = q * 512 + s * 32 + ct * 16 + lo;
        int k = kt * 32 + hi * 8;
        const float* src = W_hh + (size_t)col * NH + k;
        __align__(16) unsigned short o[8];
#pragma unroll
        for (int j = 0; j < 8; ++j) o[j] = f2bf(src[j]);
        int ba = (R << 10) + ((kt * 64 + hi * 16) ^ ((lo & 7) << 4));
        *(uint4*)((char*)Wimg2 + ((size_t)s << 17) + ba) = *(const uint4*)o;
    }
}

// ---------- small fp32-out GEMM for gx (B-panel-once, A direct) ---------------
__launch_bounds__(256)
__global__ void gxgemm(const unsigned short* __restrict__ Abf,
                       const unsigned short* __restrict__ Bbf,
                       const float* __restrict__ bias1, const float* __restrict__ bias2,
                       float* __restrict__ outf) {
    __shared__ __align__(16) char Bs[131072];   // [128][512] bf16, XOR-swizzled
    int m0 = blockIdx.y * 128, n0 = blockIdx.x * 128;
    int tid = threadIdx.x;
    int lane = tid & 63, w = tid >> 6;
    int wy = w >> 1, wx = w & 1;

#pragma unroll 4
    for (int p = 0; p < 32; ++p) {
        int row = (tid >> 6) + (p << 2);
        uint4 v = *(const uint4*)(Bbf + ((size_t)(n0 + row) << 9) + ((tid & 63) << 3));
        int ba = (row << 10) + ((tid & 63) << 4); ba ^= (row & 7) << 4;
        *(uint4*)(Bs + ba) = v;
    }
    const unsigned short* aptr[4];
#pragma unroll
    for (int rt = 0; rt < 4; ++rt)
        aptr[rt] = Abf + ((size_t)(m0 + (wy << 6) + (rt << 4) + (lane & 15)) << 9);

    f32x4 acc[4][4];
#pragma unroll
    for (int i = 0; i < 4; ++i)
#pragma unroll
        for (int j = 0; j < 4; ++j) acc[i][j] = (f32x4){0.f, 0.f, 0.f, 0.f};
    __syncthreads();

#pragma unroll 4
    for (int ks = 0; ks < 16; ++ks) {
        int koff = (ks << 5) + ((lane >> 4) << 3);
        bf16x8 bq[4];
#pragma unroll
        for (int ct = 0; ct < 4; ++ct) {
            int brow = (wx << 6) + (ct << 4) + (lane & 15);
            int bb = (brow << 10) + (koff << 1); bb ^= (brow & 7) << 4;
            bq[ct] = *(const bf16x8*)(Bs + bb);
        }
#pragma unroll
        for (int rt = 0; rt < 4; ++rt) {
            bf16x8 aq = *(const bf16x8*)(aptr[rt] + koff);
#pragma unroll
            for (int ct = 0; ct < 4; ++ct)
                acc[rt][ct] = __builtin_amdgcn_mfma_f32_16x16x32_bf16(aq, bq[ct], acc[rt][ct], 0, 0, 0);
        }
    }
#pragma unroll
    for (int rt = 0; rt < 4; ++rt)
#pragma unroll
        for (int ct = 0; ct < 4; ++ct) {
            int n = n0 + (wx << 6) + (ct << 4) + (lane & 15);
            float badd = bias1[n] + bias2[n];
#pragma unroll
            for (int ri = 0; ri < 4; ++ri) {
                int m = m0 + (wy << 6) + (rt << 4) + ((lane >> 4) << 2) + ri;
                outf[(size_t)m * NG + n] = acc[rt][ct][ri] + badd;
            }
        }
}

// ---------- pipelined MFMA GEMM (m97-style, global_load_lds dbuf) -------------
// C(Mact x N) = A @ B^T, K=512. 128x128 tile, BK=64, 4 waves, 64KB LDS.
// AMODE 0: A row m from Abf (clamped).  AMODE 1: A row m = Aemb + ridx[m]*512.
// EPI 0: gallc permuted write + gx fold:  outb[m][ (n&511)*4 + n>>9 ] = bf16(v+gx[b][n])
// EPI 1: preds scatter via rowlist + rowsum exp-atomics
template <int AMODE, int EPI>
__launch_bounds__(256)
__global__ void pgemm(const unsigned short* __restrict__ Abf,
                      const int* __restrict__ ridx,
                      const unsigned short* __restrict__ Aemb,
                      const unsigned short* __restrict__ Bbf,
                      int N,
                      const int* __restrict__ mact_p,
                      const float* __restrict__ bias1,   // EPI1: b_out; EPI0: gx[256][2048]
                      const int* __restrict__ rowlist,
                      float* __restrict__ outf,
                      unsigned short* __restrict__ outb,
                      float* __restrict__ rowsum) {
    __shared__ __align__(16) char lds[65536];   // A[2][16K] | B[2][16K]
    int Mact = *mact_p;
    int m0 = blockIdx.y * 128;
    if (m0 >= Mact) return;
    int n0 = blockIdx.x * 128;
    int tid = threadIdx.x;
    int lane = tid & 63, w = tid >> 6;
    int wy = w >> 1, wx = w & 1;
    int hi = lane >> 4, lo = lane & 15;

    // A-row source pointers for this thread's 4 staging rows
    const char* asrc[4];
#pragma unroll
    for (int i = 0; i < 4; ++i) {
        int p = (i << 8) + tid;
        int ma = m0 + (p >> 3); if (ma > Mact - 1) ma = Mact - 1;
        if (AMODE == 0) asrc[i] = (const char*)Abf + ((size_t)ma << 10);
        else            asrc[i] = (const char*)Aemb + ((size_t)ridx[ma] << 10);
    }

    auto stage = [&](int kt, int buf) {
#pragma unroll
        for (int i = 0; i < 4; ++i) {
            int p = (i << 8) + tid;
            int row = p >> 3, sc = (p & 7) ^ (row & 7);
            gl2lds16(asrc[i] + (kt << 7) + (sc << 4), lds + (buf << 14) + (p << 4));
        }
#pragma unroll
        for (int i = 0; i < 4; ++i) {
            int p = (i << 8) + tid;
            int row = p >> 3, sc = (p & 7) ^ (row & 7);
            int nb = n0 + row; if (nb > N - 1) nb = N - 1;
            gl2lds16((const char*)Bbf + ((size_t)nb << 10) + (kt << 7) + (sc << 4),
                     lds + 32768 + (buf << 14) + (p << 4));
        }
    };

    f32x4 acc[4][4];
#pragma unroll
    for (int i = 0; i < 4; ++i)
#pragma unroll
        for (int j = 0; j < 4; ++j) acc[i][j] = (f32x4){0.f, 0.f, 0.f, 0.f};

    stage(0, 0);
    __syncthreads();

    for (int kt = 0; kt < 8; ++kt) {
        int buf = kt & 1;
        if (kt < 7) stage(kt + 1, buf ^ 1);
#pragma unroll
        for (int kc = 0; kc < 2; ++kc) {
            bf16x8 aq[4], bq[4];
#pragma unroll
            for (int rt = 0; rt < 4; ++rt) {
                int ra = (wy << 6) + (rt << 4) + lo;
                int cha = ((kc << 2) + hi) ^ (ra & 7);
                aq[rt] = *(const bf16x8*)(lds + (buf << 14) + (ra << 7) + (cha << 4));
                int cb = (wx << 6) + (rt << 4) + lo;
                int chb = ((kc << 2) + hi) ^ (cb & 7);
                bq[rt] = *(const bf16x8*)(lds + 32768 + (buf << 14) + (cb << 7) + (chb << 4));
            }
#pragma unroll
            for (int rt = 0; rt < 4; ++rt)
#pragma unroll
                for (int ct = 0; ct < 4; ++ct)
                    acc[rt][ct] = __builtin_amdgcn_mfma_f32_16x16x32_bf16(aq[rt], bq[ct], acc[rt][ct], 0, 0, 0);
        }
        __syncthreads();
    }

    if (EPI == 0) {
        // gallc permuted write + gx fold (N=2048, all n in-range)
#pragma unroll
        for (int rt = 0; rt < 4; ++rt)
#pragma unroll
            for (int ct = 0; ct < 4; ++ct) {
                int n = n0 + (wx << 6) + (ct << 4) + lo;
#pragma unroll
                for (int ri = 0; ri < 4; ++ri) {
                    int m = m0 + (wy << 6) + (rt << 4) + (hi << 2) + ri;
                    if (m < Mact) {
                        int b = rowlist[m] & 255;
                        float v = acc[rt][ct][ri] + bias1[(size_t)b * NG + n];
                        outb[(size_t)m * NG + ((n & 511) << 2) + (n >> 9)] = f2bf(v);
                    }
                }
            }
    } else {
        // preds scatter + per-row sum(exp) atomics
#pragma unroll
        for (int rt = 0; rt < 4; ++rt) {
            float es4[4] = {0.f, 0.f, 0.f, 0.f};
#pragma unroll
            for (int ct = 0; ct < 4; ++ct) {
                int n = n0 + (wx << 6) + (ct << 4) + lo;
                bool okn = (n < N);
                float bo = okn ? bias1[n] : 0.f;
#pragma unroll
                for (int ri = 0; ri < 4; ++ri) {
                    int m = m0 + (wy << 6) + (rt << 4) + (hi << 2) + ri;
                    float v = acc[rt][ct][ri] + bo;
                    if (okn && m < Mact) {
                        int r = rowlist[m];
                        outf[(size_t)(r & 255) * PRED_B + (size_t)(r >> 8) * NV + n] = v;
                        es4[ri] += __expf(v);
                    }
                }
            }
#pragma unroll
            for (int ri = 0; ri < 4; ++ri) {
                float s = es4[ri];
                s += __shfl_xor(s, 1); s += __shfl_xor(s, 2);
                s += __shfl_xor(s, 4); s += __shfl_xor(s, 8);
                if (lo == 0) {
                    int m = m0 + (wy << 6) + (rt << 4) + (hi << 2) + ri;
                    if (m < Mact) atomicAdd(&rowsum[m], s);
                }
            }
        }
    }
}

// ---------- fused LSTM: W-resident, d-sliced, single-writer flag slots --------
__launch_bounds__(256, 1)
__global__ void lstmy_k(const unsigned short* __restrict__ Wimg2,  // [16][128KB]
                        const unsigned short* __restrict__ gallc,  // [n_active][512][4]
                        unsigned short* __restrict__ hx,           // [2][16][16KB image]
                        unsigned short* __restrict__ h_allc,       // [n_active][512]
                        int* __restrict__ flags,                   // [16][16]
                        const int* __restrict__ cnt,
                        const int* __restrict__ start) {
    __shared__ __align__(16) char Wlds[131072];
    __shared__ __align__(16) char hlds[16384];
    __shared__ float Gs[4 * 16 * 32];
    __shared__ __align__(16) unsigned short hstg[16 * 32];   // 1KB slice staging
    int tid = threadIdx.x;
    int g = blockIdx.x & 15, s = blockIdx.x >> 4;
    int lane = tid & 63, w = tid >> 6;          // wave w = gate quarter q
    int hi = lane >> 4, lo = lane & 15;
    int q = w;

    // load W slice once (linear copy of pre-swizzled image)
    {
        const char* wsrc = (const char*)Wimg2 + ((size_t)s << 17) + tid * 16;
#pragma unroll 8
        for (int r = 0; r < 32; ++r)
            gl2lds16(wsrc + r * 4096, Wlds + tid * 16 + r * 4096);
    }
    // zero h image
    {
        uint4 z = make_uint4(0u, 0u, 0u, 0u);
        *(uint4*)(hlds + tid * 16) = z;
        *(uint4*)(hlds + 4096 + tid * 16) = z;
        *(uint4*)(hlds + 8192 + tid * 16) = z;
        *(uint4*)(hlds + 12288 + tid * 16) = z;
    }
    asm volatile("s_waitcnt vmcnt(0)" ::: "memory");
    __syncthreads();

    int row = tid >> 4, d0 = tid & 15;          // elementwise ownership
    float creg[2] = {0.f, 0.f};

    for (int t = 0; t < NT; ++t) {
        int cnt_t = cnt[t];
        if (16 * g >= cnt_t) break;
        int nrow = cnt_t - 16 * g; if (nrow > 16) nrow = 16;
        int pos0 = start[t] + 16 * g;

        // issue x-preact loads early (stable data, plain cached loads)
        int rr = row < nrow ? row : nrow - 1;
        const unsigned short* gp = gallc + ((size_t)(pos0 + rr) << 11);
        uint2 gq0 = *(const uint2*)(gp + (s * 32 + d0) * 4);
        uint2 gq1 = *(const uint2*)(gp + (s * 32 + d0 + 16) * 4);

        if (t > 0) {
            // wait for all 16 producers of group g to have posted step t-1
            if (tid < 16) {
                const int* fp = flags + g * 16 + tid;
                int f;
                do {
                    asm volatile("global_load_dword %0, %1, off sc0 sc1\n\t"
                                 "s_waitcnt vmcnt(0)"
                                 : "=v"(f) : "v"(fp) : "memory");
                } while (f < t);
            }
            __syncthreads();
            // load full-h 16KB image (L3-coherent), stage into LDS
            const char* hsrc = (const char*)hx +
                ((size_t)(((t - 1) & 1) * 16 + g) << 14) + tid * 16;
            uint4 va, vb, vc, vd;
            asm volatile(
                "global_load_dwordx4 %0, %4, off sc0 sc1\n\t"
                "global_load_dwordx4 %1, %5, off sc0 sc1\n\t"
                "global_load_dwordx4 %2, %6, off sc0 sc1\n\t"
                "global_load_dwordx4 %3, %7, off sc0 sc1\n\t"
                "s_waitcnt vmcnt(0)"
                : "=&v"(va), "=&v"(vb), "=&v"(vc), "=&v"(vd)
                : "v"(hsrc), "v"(hsrc + 4096), "v"(hsrc + 8192), "v"(hsrc + 12288)
                : "memory");
            *(uint4*)(hlds + tid * 16) = va;
            *(uint4*)(hlds + 4096 + tid * 16) = vb;
            *(uint4*)(hlds + 8192 + tid * 16) = vc;
            *(uint4*)(hlds + 12288 + tid * 16) = vd;
            __syncthreads();
        }

        // MFMA: 16 rows x 32 cols (this wave's quarter q), K=512
        f32x4 acc[2];
        acc[0] = (f32x4){0.f, 0.f, 0.f, 0.f};
        acc[1] = (f32x4){0.f, 0.f, 0.f, 0.f};
#pragma unroll 4
        for (int kt = 0; kt < 16; ++kt) {
            int ab = (lo << 10) + (((kt << 5) + (hi << 3)) << 1); ab ^= (lo & 7) << 4;
            bf16x8 aq = *(const bf16x8*)(hlds + ab);
#pragma unroll
            for (int ct = 0; ct < 2; ++ct) {
                int R = (q * 2 + ct) * 16 + lo;
                int bb = (R << 10) + ((kt * 64 + hi * 16) ^ ((lo & 7) << 4));
                bf16x8 bq = *(const bf16x8*)(Wlds + bb);
                acc[ct] = __builtin_amdgcn_mfma_f32_16x16x32_bf16(aq, bq, acc[ct], 0, 0, 0);
            }
        }
        // gate exchange: Gs[q][row][d']
#pragma unroll
        for (int ct = 0; ct < 2; ++ct)
#pragma unroll
            for (int ri = 0; ri < 4; ++ri)
                Gs[(q * 16 + hi * 4 + ri) * 32 + ct * 16 + lo] = acc[ct][ri];
        __syncthreads();

        // elementwise: this thread owns (row, d0) and (row, d0+16); stage to LDS
        bool act = row < nrow;
#pragma unroll
        for (int p = 0; p < 2; ++p) {
            int dp = d0 + p * 16;
            int hd = s * 32 + dp;
            const unsigned short* gq = (const unsigned short*)(p ? &gq1 : &gq0);
            float iv = Gs[(0 * 16 + row) * 32 + dp] + bf2f(gq[0]);
            float fv = Gs[(1 * 16 + row) * 32 + dp] + bf2f(gq[1]);
            float gv = Gs[(2 * 16 + row) * 32 + dp] + bf2f(gq[2]);
            float ov = Gs[(3 * 16 + row) * 32 + dp] + bf2f(gq[3]);
            float i_ = 1.f / (1.f + __expf(-iv));
            float f_ = 1.f / (1.f + __expf(-fv));
            float o_ = 1.f / (1.f + __expf(-ov));
            float ea = __expf(-2.f * fabsf(gv));
            float th = (1.f - ea) / (1.f + ea);
            th = (gv < 0.f) ? -th : th;
            float cn = f_ * creg[p] + i_ * th;
            float ec = __expf(-2.f * fabsf(cn));
            float tc = (1.f - ec) / (1.f + ec);
            tc = (cn < 0.f) ? -tc : tc;
            float hn = o_ * tc;
            unsigned short hv;
            if (act) {
                creg[p] = cn;
                hv = f2bf(hn);
            } else {
                int hoff = ((row << 10) + (hd << 1)) ^ ((row & 7) << 4);
                hv = *(const unsigned short*)(hlds + hoff);   // forward h[t-1]
            }
            hstg[row * 32 + dp] = hv;
        }
        __syncthreads();

        // wide image store (critical path) -> flag post -> h_allc (off path)
        uint2 v0, v1;
        int crow = tid >> 2, j = tid & 3;
        if (tid < 64) {
            v0 = *(const uint2*)(hstg + crow * 32 + j * 8);
            v1 = *(const uint2*)(hstg + crow * 32 + j * 8 + 4);
            char* himg = (char*)hx + ((size_t)((t & 1) * 16 + g) << 14);
            int dstoff = (crow << 10) + ((((s << 2) + j) ^ (crow & 7)) << 4);
            asm volatile("global_store_dwordx2 %0, %2, off sc0 sc1\n\t"
                         "global_store_dwordx2 %1, %3, off sc0 sc1"
                         :: "v"(himg + dstoff), "v"(himg + dstoff + 8),
                            "v"(v0), "v"(v1) : "memory");
        }
        asm volatile("s_waitcnt vmcnt(0)" ::: "memory");
        __syncthreads();   // all lanes' image stores drained before post
        if (tid == 0) {
            int fv = t + 1;
            asm volatile("global_store_dword %0, %1, off sc0 sc1"
                         :: "v"(flags + g * 16 + s), "v"(fv) : "memory");
        }
        // h_allc store: consumed only after kernel end, keep off critical path
        if (tid < 64 && crow < nrow) {
            unsigned short* hap = h_allc + (size_t)(pos0 + crow) * NH + s * 32 + j * 8;
            *(uint2*)hap = v0;
            *(uint2*)(hap + 4) = v1;
        }
    }
}

// ---------- final pass: preds = logit - log(rowsum); zero inactive + t=30 -----
__global__ void norm_k(float* __restrict__ out, const float* __restrict__ rowsum,
                       const int* __restrict__ cnt, const int* __restrict__ start) {
    int r = blockIdx.x;          // 0..(31*256-1), r = t*256+b, t in [0,31)
    int t = r >> 8, b = r & 255;
    bool act = (t < NT) && (b < cnt[t]);
    float lse = 0.f;
    if (act) lse = logf(rowsum[start[t] + b]);
    float4* row = (float4*)(out + (size_t)b * PRED_B + (size_t)t * NV);
    for (int v4 = threadIdx.x; v4 < NV / 4; v4 += 256) {
        float4 x;
        if (act) {
            x = row[v4];
            x.x -= lse; x.y -= lse; x.z -= lse; x.w -= lse;
        } else {
            x.x = 0.f; x.y = 0.f; x.z = 0.f; x.w = 0.f;
        }
        row[v4] = x;
    }
}

extern "C" void kernel_launch(void* const* d_in, const int* in_sizes, int n_in,
                              void* d_out, int out_size, void* d_ws, size_t ws_size,
                              hipStream_t stream) {
    const float* gimg  = (const float*)d_in[0];
    const int*   w_in  = (const int*)d_in[1];
    const int*   lens  = (const int*)d_in[2];
    const float* emb   = (const float*)d_in[3];
    const float* W_ih  = (const float*)d_in[4];
    const float* W_hh  = (const float*)d_in[5];
    const float* b_ih  = (const float*)d_in[6];
    const float* b_hh  = (const float*)d_in[7];
    const float* W_out = (const float*)d_in[8];
    const float* b_out = (const float*)d_in[9];
    float* out = (float*)d_out;

    char* p = (char*)d_ws;
    auto alloc = [&](size_t bytes) -> char* {
        char* r = p;
        p += (bytes + 255) & ~(size_t)255;
        return r;
    };
    int*   order   = (int*)alloc(NB * 4);
    int*   wsort   = (int*)alloc(NB * ML * 4);
    int*   cnt     = (int*)alloc(NT * 4);
    int*   start   = (int*)alloc((NT + 1) * 4);
    int*   flags   = (int*)alloc(256 * 4);
    int*   rowlist = (int*)alloc((size_t)NT * NB * 4);
    int*   rowwc   = (int*)alloc((size_t)NT * NB * 4);
    float* gx      = (float*)alloc((size_t)NB * NG * 4);
    float* rowsum  = (float*)alloc((size_t)NT * NB * 4);
    unsigned short* g_sb   = (unsigned short*)alloc((size_t)NB * NE * 2);
    unsigned short* hx     = (unsigned short*)alloc((size_t)2 * 16 * 16384);
    unsigned short* h_allc = (unsigned short*)alloc((size_t)NT * NB * NH * 2);
    unsigned short* Wimg2  = (unsigned short*)alloc((size_t)NG * NH * 2);
    unsigned short* Wxl    = (unsigned short*)alloc((size_t)NG * NE * 2);
    unsigned short* Wxb    = (unsigned short*)alloc((size_t)NG * NE * 2);
    unsigned short* Wob    = (unsigned short*)alloc((size_t)NV * NH * 2);
    unsigned short* embb   = (unsigned short*)alloc((size_t)NV * NE * 2);
    unsigned short* gallc  = (unsigned short*)alloc((size_t)NT * NB * NG * 2);
    int* nact = start + NT;   // n_active lives at start[30]

    sort_k<<<1, 256, 0, stream>>>(lens, order, cnt, start, flags, out + OFF_DEC);
    gather_k<<<NB, 256, 0, stream>>>(gimg, w_in, order, g_sb, wsort, out + OFF_TGT);
    rowlist_k<<<NT, 256, 0, stream>>>(wsort, cnt, start, rowlist, rowwc, rowsum);
    prep_k<<<12560, 256, 0, stream>>>(W_ih, W_hh, W_out, emb, Wxl, Wxb, Wob, embb, Wimg2);

    // gx = g_sb @ Wxl^T + b_ih + b_hh     (256 x 2048, K=512, fp32 out)
    gxgemm<<<dim3(NG / 128, NB / 128), 256, 0, stream>>>(g_sb, Wxl, b_ih, b_hh, gx);

    // gallc[pos][d][q] = bf16( emb[rowwc[pos]] @ Wxb^T + gx[b] )   (n_active x 2048)
    pgemm<1, 0><<<dim3(NG / 128, NT * NB / 128), 256, 0, stream>>>(
        nullptr, rowwc, embb, Wxb, NG, nact, gx, rowlist, nullptr, gallc, nullptr);

    // fused 30-step recurrence: W-resident, single-writer flag sync (coop)
    {
        void* cargs[] = { (void*)&Wimg2, (void*)&gallc, (void*)&hx, (void*)&h_allc,
                          (void*)&flags, (void*)&cnt, (void*)&start };
        (void)hipLaunchCooperativeKernel((void*)lstmy_k, dim3(256), dim3(256), cargs, 0, stream);
    }

    // logits = h_allc @ Wob^T + b_out -> preds scatter + rowsum exp-atomics
    pgemm<0, 1><<<dim3((NV + 127) / 128, NT * NB / 128), 256, 0, stream>>>(
        h_allc, nullptr, nullptr, Wob, NV, nact, b_out, rowlist, out, nullptr, rowsum);

    norm_k<<<(NT + 1) * NB, 256, 0, stream>>>(out, rowsum, cnt, start);
}

// Round 11
// 423.935 us; speedup vs baseline: 5.4619x; 1.0262x over previous
//
#include <hip/hip_runtime.h>
#include <hip/hip_bf16.h>
#include <math.h>

// Problem constants
#define NB   256      // batch
#define ML   31       // MAX_LEN
#define NT   30       // T = MAX_LEN-1 decode steps
#define NV   10000    // vocab
#define NH   512      // hidden
#define NE   512      // embed
#define NG   2048     // 4*H gates

// Output layout (floats): preds (256,31,10000) | target (256,30) | dec_len (256,)
#define OFF_TGT  (256LL*31LL*10000LL)
#define OFF_DEC  (OFF_TGT + 256LL*30LL)
#define PRED_B   (31LL*10000LL)

typedef __attribute__((ext_vector_type(8))) short bf16x8;
typedef __attribute__((ext_vector_type(4))) float f32x4;

__device__ inline unsigned short f2bf(float f) {
    unsigned int x = __float_as_uint(f);
    unsigned int r = x + 0x7FFFu + ((x >> 16) & 1u);   // RNE
    return (unsigned short)(r >> 16);
}
__device__ inline float bf2f(unsigned short u) {
    return __uint_as_float((unsigned int)u << 16);
}

__device__ inline void gl2lds16(const void* g, void* l) {
    __builtin_amdgcn_global_load_lds(
        (const __attribute__((address_space(1))) unsigned int*)g,
        (__attribute__((address_space(3))) unsigned int*)l, 16, 0, 0);
}

// ---------- sort: stable descending argsort + counts + zero flags -------------
__global__ void sort_k(const int* __restrict__ lens, int* __restrict__ order,
                       int* __restrict__ cnt, int* __restrict__ start,
                       int* __restrict__ flags, float* __restrict__ out_dec) {
    __shared__ int sd[NB];
    int i = threadIdx.x;
    flags[i] = 0;
    int li = lens[i];
    int r = 0;
    for (int j = 0; j < NB; j++) {
        int lj = lens[j];
        r += (lj > li) || (lj == li && j < i);
    }
    order[r] = i;
    out_dec[r] = (float)(li - 1);
    sd[r] = li - 1;
    __syncthreads();
    if (i < NT) {
        int c = 0;
        for (int b = 0; b < NB; b++) c += (sd[b] > i);
        cnt[i] = c;
    }
    __syncthreads();
    if (i == 0) {
        int s = 0;
        for (int t = 0; t < NT; t++) { start[t] = s; s += cnt[t]; }
        start[NT] = s;                 // n_active
    }
}

// ---------- gather sorted rows (bf16 image), emit target ----------------------
__global__ void gather_k(const float* __restrict__ gimg, const int* __restrict__ w_in,
                         const int* __restrict__ order,
                         unsigned short* __restrict__ g_sb, int* __restrict__ wsort,
                         float* __restrict__ out_tgt) {
    int r = blockIdx.x, tid = threadIdx.x;
    int o = order[r];
    for (int e = tid; e < NE; e += 256)
        g_sb[r * NE + e] = f2bf(gimg[o * NE + e]);
    if (tid < ML) wsort[r * ML + tid] = w_in[o * ML + tid];
    if (tid < NT) out_tgt[r * NT + tid] = (float)w_in[o * ML + tid + 1];
}

// ---------- compact active-row lists + zero rowsum ----------------------------
__global__ void rowlist_k(const int* __restrict__ wsort, const int* __restrict__ cnt,
                          const int* __restrict__ start,
                          int* __restrict__ rowlist, int* __restrict__ rowwc,
                          float* __restrict__ rowsum) {
    int t = blockIdx.x, b = threadIdx.x;
    rowsum[t * 256 + b] = 0.f;
    if (b < cnt[t]) {
        int pos = start[t] + b;
        rowlist[pos] = t * 256 + b;
        rowwc[pos] = wsort[b * ML + t];
    }
}

// ---------- fused preamble conversions ----------------------------------------
__global__ void prep_k(const float* __restrict__ W_ih, const float* __restrict__ W_hh,
                       const float* __restrict__ W_out, const float* __restrict__ emb,
                       unsigned short* __restrict__ Wxl, unsigned short* __restrict__ Wxb,
                       unsigned short* __restrict__ Wob, unsigned short* __restrict__ embb,
                       unsigned short* __restrict__ Wimg2) {
    int bid = blockIdx.x, tid = threadIdx.x;
    if (bid < 2048) {
        int koff = (bid < 1024) ? 0 : NE;
        unsigned short* dst = (bid < 1024) ? Wxl : Wxb;
        int gid = ((bid & 1023) << 8) + tid;        // 2048*128 float4 chunks
        int j = gid >> 7, k4 = gid & 127;
        float4 v = *(const float4*)(W_ih + (size_t)j * (2 * NE) + koff + k4 * 4);
        ushort4 o;
        o.x = f2bf(v.x); o.y = f2bf(v.y); o.z = f2bf(v.z); o.w = f2bf(v.w);
        *(ushort4*)(dst + (size_t)j * NE + k4 * 4) = o;
    } else if (bid < 12048) {
        const float* src = (bid < 7048) ? W_out : emb;
        unsigned short* dst = (bid < 7048) ? Wob : embb;
        int gid = ((bid < 7048 ? bid - 2048 : bid - 7048) << 8) + tid;
        float4 v = ((const float4*)src)[gid];
        ushort4 o;
        o.x = f2bf(v.x); o.y = f2bf(v.y); o.z = f2bf(v.z); o.w = f2bf(v.w);
        ((ushort4*)dst)[gid] = o;
    } else {
        int gid = ((bid - 12048) << 8) + tid;       // 131072 = 16s*128R*16kt*4hi
        int hi = gid & 3, kt = (gid >> 2) & 15, R = (gid >> 6) & 127, s = gid >> 13;
        int q = R >> 5, ct = (R >> 4) & 1, lo = R & 15;
        int col = q * 512 + s * 32 + ct * 16 + lo;
        int k = kt * 32 + hi * 8;
        const float* src = W_hh + (size_t)col * NH + k;
        __align__(16) unsigned short o[8];
#pragma unroll
        for (int j = 0; j < 8; ++j) o[j] = f2bf(src[j]);
        int ba = (R << 10) + ((kt * 64 + hi * 16) ^ ((lo & 7) << 4));
        *(uint4*)((char*)Wimg2 + ((size_t)s << 17) + ba) = *(const uint4*)o;
    }
}

// ---------- small fp32-out GEMM for gx (B-panel-once, A direct) ---------------
__launch_bounds__(256)
__global__ void gxgemm(const unsigned short* __restrict__ Abf,
                       const unsigned short* __restrict__ Bbf,
                       const float* __restrict__ bias1, const float* __restrict__ bias2,
                       float* __restrict__ outf) {
    __shared__ __align__(16) char Bs[131072];   // [128][512] bf16, XOR-swizzled
    int m0 = blockIdx.y * 128, n0 = blockIdx.x * 128;
    int tid = threadIdx.x;
    int lane = tid & 63, w = tid >> 6;
    int wy = w >> 1, wx = w & 1;

#pragma unroll 4
    for (int p = 0; p < 32; ++p) {
        int row = (tid >> 6) + (p << 2);
        uint4 v = *(const uint4*)(Bbf + ((size_t)(n0 + row) << 9) + ((tid & 63) << 3));
        int ba = (row << 10) + ((tid & 63) << 4); ba ^= (row & 7) << 4;
        *(uint4*)(Bs + ba) = v;
    }
    const unsigned short* aptr[4];
#pragma unroll
    for (int rt = 0; rt < 4; ++rt)
        aptr[rt] = Abf + ((size_t)(m0 + (wy << 6) + (rt << 4) + (lane & 15)) << 9);

    f32x4 acc[4][4];
#pragma unroll
    for (int i = 0; i < 4; ++i)
#pragma unroll
        for (int j = 0; j < 4; ++j) acc[i][j] = (f32x4){0.f, 0.f, 0.f, 0.f};
    __syncthreads();

#pragma unroll 4
    for (int ks = 0; ks < 16; ++ks) {
        int koff = (ks << 5) + ((lane >> 4) << 3);
        bf16x8 bq[4];
#pragma unroll
        for (int ct = 0; ct < 4; ++ct) {
            int brow = (wx << 6) + (ct << 4) + (lane & 15);
            int bb = (brow << 10) + (koff << 1); bb ^= (brow & 7) << 4;
            bq[ct] = *(const bf16x8*)(Bs + bb);
        }
#pragma unroll
        for (int rt = 0; rt < 4; ++rt) {
            bf16x8 aq = *(const bf16x8*)(aptr[rt] + koff);
#pragma unroll
            for (int ct = 0; ct < 4; ++ct)
                acc[rt][ct] = __builtin_amdgcn_mfma_f32_16x16x32_bf16(aq, bq[ct], acc[rt][ct], 0, 0, 0);
        }
    }
#pragma unroll
    for (int rt = 0; rt < 4; ++rt)
#pragma unroll
        for (int ct = 0; ct < 4; ++ct) {
            int n = n0 + (wx << 6) + (ct << 4) + (lane & 15);
            float badd = bias1[n] + bias2[n];
#pragma unroll
            for (int ri = 0; ri < 4; ++ri) {
                int m = m0 + (wy << 6) + (rt << 4) + ((lane >> 4) << 2) + ri;
                outf[(size_t)m * NG + n] = acc[rt][ct][ri] + badd;
            }
        }
}

// ---------- pipelined MFMA GEMM (m97-style, global_load_lds dbuf) -------------
// Grid: x = m-tile, y = n-tile (consecutive blocks share B panel -> L2 reuse).
// EPI 0: gallc permuted write + gx fold
// EPI 1: bf16 logits to outb[m*NV+n] + rowsum exp-atomics
template <int AMODE, int EPI>
__launch_bounds__(256)
__global__ void pgemm(const unsigned short* __restrict__ Abf,
                      const int* __restrict__ ridx,
                      const unsigned short* __restrict__ Aemb,
                      const unsigned short* __restrict__ Bbf,
                      int N,
                      const int* __restrict__ mact_p,
                      const float* __restrict__ bias1,   // EPI1: b_out; EPI0: gx[256][2048]
                      const int* __restrict__ rowlist,
                      unsigned short* __restrict__ outb,
                      float* __restrict__ rowsum) {
    __shared__ __align__(16) char lds[65536];   // A[2][16K] | B[2][16K]
    int Mact = *mact_p;
    int m0 = blockIdx.x * 128;
    if (m0 >= Mact) return;
    int n0 = blockIdx.y * 128;
    int tid = threadIdx.x;
    int lane = tid & 63, w = tid >> 6;
    int wy = w >> 1, wx = w & 1;
    int hi = lane >> 4, lo = lane & 15;

    const char* asrc[4];
#pragma unroll
    for (int i = 0; i < 4; ++i) {
        int p = (i << 8) + tid;
        int ma = m0 + (p >> 3); if (ma > Mact - 1) ma = Mact - 1;
        if (AMODE == 0) asrc[i] = (const char*)Abf + ((size_t)ma << 10);
        else            asrc[i] = (const char*)Aemb + ((size_t)ridx[ma] << 10);
    }

    auto stage = [&](int kt, int buf) {
#pragma unroll
        for (int i = 0; i < 4; ++i) {
            int p = (i << 8) + tid;
            int row = p >> 3, sc = (p & 7) ^ (row & 7);
            gl2lds16(asrc[i] + (kt << 7) + (sc << 4), lds + (buf << 14) + (p << 4));
        }
#pragma unroll
        for (int i = 0; i < 4; ++i) {
            int p = (i << 8) + tid;
            int row = p >> 3, sc = (p & 7) ^ (row & 7);
            int nb = n0 + row; if (nb > N - 1) nb = N - 1;
            gl2lds16((const char*)Bbf + ((size_t)nb << 10) + (kt << 7) + (sc << 4),
                     lds + 32768 + (buf << 14) + (p << 4));
        }
    };

    f32x4 acc[4][4];
#pragma unroll
    for (int i = 0; i < 4; ++i)
#pragma unroll
        for (int j = 0; j < 4; ++j) acc[i][j] = (f32x4){0.f, 0.f, 0.f, 0.f};

    stage(0, 0);
    __syncthreads();

    for (int kt = 0; kt < 8; ++kt) {
        int buf = kt & 1;
        if (kt < 7) stage(kt + 1, buf ^ 1);
#pragma unroll
        for (int kc = 0; kc < 2; ++kc) {
            bf16x8 aq[4], bq[4];
#pragma unroll
            for (int rt = 0; rt < 4; ++rt) {
                int ra = (wy << 6) + (rt << 4) + lo;
                int cha = ((kc << 2) + hi) ^ (ra & 7);
                aq[rt] = *(const bf16x8*)(lds + (buf << 14) + (ra << 7) + (cha << 4));
                int cb = (wx << 6) + (rt << 4) + lo;
                int chb = ((kc << 2) + hi) ^ (cb & 7);
                bq[rt] = *(const bf16x8*)(lds + 32768 + (buf << 14) + (cb << 7) + (chb << 4));
            }
#pragma unroll
            for (int rt = 0; rt < 4; ++rt)
#pragma unroll
                for (int ct = 0; ct < 4; ++ct)
                    acc[rt][ct] = __builtin_amdgcn_mfma_f32_16x16x32_bf16(aq[rt], bq[ct], acc[rt][ct], 0, 0, 0);
        }
        __syncthreads();
    }

    if (EPI == 0) {
        // gallc permuted write + gx fold (N=2048, all n in-range)
#pragma unroll
        for (int rt = 0; rt < 4; ++rt)
#pragma unroll
            for (int ct = 0; ct < 4; ++ct) {
                int n = n0 + (wx << 6) + (ct << 4) + lo;
#pragma unroll
                for (int ri = 0; ri < 4; ++ri) {
                    int m = m0 + (wy << 6) + (rt << 4) + (hi << 2) + ri;
                    if (m < Mact) {
                        int b = rowlist[m] & 255;
                        float v = acc[rt][ct][ri] + bias1[(size_t)b * NG + n];
                        outb[(size_t)m * NG + ((n & 511) << 2) + (n >> 9)] = f2bf(v);
                    }
                }
            }
    } else {
        // bf16 logits (compact) + per-row sum(exp) atomics
#pragma unroll
        for (int rt = 0; rt < 4; ++rt) {
            float es4[4] = {0.f, 0.f, 0.f, 0.f};
#pragma unroll
            for (int ct = 0; ct < 4; ++ct) {
                int n = n0 + (wx << 6) + (ct << 4) + lo;
                bool okn = (n < N);
                float bo = okn ? bias1[n] : 0.f;
#pragma unroll
                for (int ri = 0; ri < 4; ++ri) {
                    int m = m0 + (wy << 6) + (rt << 4) + (hi << 2) + ri;
                    float v = acc[rt][ct][ri] + bo;
                    if (okn && m < Mact) {
                        outb[(size_t)m * NV + n] = f2bf(v);
                        es4[ri] += __expf(v);
                    }
                }
            }
#pragma unroll
            for (int ri = 0; ri < 4; ++ri) {
                float s = es4[ri];
                s += __shfl_xor(s, 1); s += __shfl_xor(s, 2);
                s += __shfl_xor(s, 4); s += __shfl_xor(s, 8);
                if (lo == 0) {
                    int m = m0 + (wy << 6) + (rt << 4) + (hi << 2) + ri;
                    if (m < Mact) atomicAdd(&rowsum[m], s);
                }
            }
        }
    }
}

// ---------- fused LSTM: W-resident, slice-contiguous image, direct A loads ----
// 256 blocks x 256 threads (coop). Block b: g = b&15 (rows [16g,16g+16)),
// s = b>>4 (h-dims [32s,32s+32), 128KB W-slice LDS-resident).
// h image per (buf,g): [16 slices][16 rows][32 dims] (1KB per slice).
// Consumers load A-frags DIRECT global->VGPR (16 parallel 16B loads), no hlds.
__launch_bounds__(256, 1)
__global__ void lstmy_k(const unsigned short* __restrict__ Wimg2,  // [16][128KB]
                        const unsigned short* __restrict__ gallc,  // [n_active][512][4]
                        unsigned short* __restrict__ hx,           // [2][16][16KB image]
                        unsigned short* __restrict__ h_allc,       // [n_active][512]
                        int* __restrict__ flags,                   // [16][16]
                        const int* __restrict__ cnt,
                        const int* __restrict__ start) {
    __shared__ __align__(16) char Wlds[131072];
    __shared__ float Gs[4 * 16 * 32];
    __shared__ __align__(16) unsigned short hstg[16 * 32];   // this block's slice
    int tid = threadIdx.x;
    int g = blockIdx.x & 15, s = blockIdx.x >> 4;
    int lane = tid & 63, w = tid >> 6;          // wave w = gate quarter q
    int hi = lane >> 4, lo = lane & 15;
    int q = w;

    // load W slice once (linear copy of pre-swizzled image)
    {
        const char* wsrc = (const char*)Wimg2 + ((size_t)s << 17) + tid * 16;
#pragma unroll 8
        for (int r = 0; r < 32; ++r)
            gl2lds16(wsrc + r * 4096, Wlds + tid * 16 + r * 4096);
    }
    asm volatile("s_waitcnt vmcnt(0)" ::: "memory");
    __syncthreads();

    int row = tid >> 4, d0 = tid & 15;          // elementwise ownership
    float creg[2] = {0.f, 0.f};

    for (int t = 0; t < NT; ++t) {
        int cnt_t = cnt[t];
        if (16 * g >= cnt_t) break;
        int nrow = cnt_t - 16 * g; if (nrow > 16) nrow = 16;
        int pos0 = start[t] + 16 * g;

        // issue x-preact loads early (stable data, plain cached loads)
        int rr = row < nrow ? row : nrow - 1;
        const unsigned short* gp = gallc + ((size_t)(pos0 + rr) << 11);
        uint2 gq0 = *(const uint2*)(gp + (s * 32 + d0) * 4);
        uint2 gq1 = *(const uint2*)(gp + (s * 32 + d0 + 16) * 4);

        f32x4 acc[2];
        acc[0] = (f32x4){0.f, 0.f, 0.f, 0.f};
        acc[1] = (f32x4){0.f, 0.f, 0.f, 0.f};

        if (t > 0) {
            // wave-level poll: all 16 producers of group g posted step t-1
            {
                const int* fp = flags + g * 16 + lo;
                int f;
                do {
                    asm volatile("global_load_dword %0, %1, off sc0 sc1\n\t"
                                 "s_waitcnt vmcnt(0)"
                                 : "=v"(f) : "v"(fp) : "memory");
                } while (__any(f < t));
            }
            // direct global->VGPR A-frag loads: 16 slices x 16B/lane, parallel
            const char* hb = (const char*)hx +
                ((size_t)(((t - 1) & 1) * 16 + g) << 14) + (lo << 6) + (hi << 4);
            uint4 hv[16];
#pragma unroll
            for (int c = 0; c < 16; ++c)
                asm volatile("global_load_dwordx4 %0, %1, off sc0 sc1"
                             : "=v"(hv[c]) : "v"(hb + (c << 10)) : "memory");
            asm volatile("s_waitcnt vmcnt(0)" ::: "memory");
            __builtin_amdgcn_sched_barrier(0);
#pragma unroll
            for (int kt = 0; kt < 16; ++kt) {
                bf16x8 aq = *(const bf16x8*)&hv[kt];
#pragma unroll
                for (int ct = 0; ct < 2; ++ct) {
                    int R = (q * 2 + ct) * 16 + lo;
                    int bb = (R << 10) + ((kt * 64 + hi * 16) ^ ((lo & 7) << 4));
                    bf16x8 bq = *(const bf16x8*)(Wlds + bb);
                    acc[ct] = __builtin_amdgcn_mfma_f32_16x16x32_bf16(aq, bq, acc[ct], 0, 0, 0);
                }
            }
        }
        // gate exchange: Gs[q][row][d']
#pragma unroll
        for (int ct = 0; ct < 2; ++ct)
#pragma unroll
            for (int ri = 0; ri < 4; ++ri)
                Gs[(q * 16 + hi * 4 + ri) * 32 + ct * 16 + lo] = acc[ct][ri];
        __syncthreads();

        // elementwise: this thread owns (row, d0) and (row, d0+16)
        bool act = row < nrow;
#pragma unroll
        for (int p = 0; p < 2; ++p) {
            int dp = d0 + p * 16;
            const unsigned short* gq = (const unsigned short*)(p ? &gq1 : &gq0);
            float iv = Gs[(0 * 16 + row) * 32 + dp] + bf2f(gq[0]);
            float fv = Gs[(1 * 16 + row) * 32 + dp] + bf2f(gq[1]);
            float gv = Gs[(2 * 16 + row) * 32 + dp] + bf2f(gq[2]);
            float ov = Gs[(3 * 16 + row) * 32 + dp] + bf2f(gq[3]);
            float i_ = 1.f / (1.f + __expf(-iv));
            float f_ = 1.f / (1.f + __expf(-fv));
            float o_ = 1.f / (1.f + __expf(-ov));
            float ea = __expf(-2.f * fabsf(gv));
            float th = (1.f - ea) / (1.f + ea);
            th = (gv < 0.f) ? -th : th;
            float cn = f_ * creg[p] + i_ * th;
            float ec = __expf(-2.f * fabsf(cn));
            float tc = (1.f - ec) / (1.f + ec);
            tc = (cn < 0.f) ? -tc : tc;
            float hn = o_ * tc;
            unsigned short hv16;
            if (act) {
                creg[p] = cn;
                hv16 = f2bf(hn);
            } else {
                hv16 = hstg[row * 32 + dp];   // forward h[t-1] (kept from prev step)
            }
            hstg[row * 32 + dp] = hv16;
        }
        __syncthreads();

        // slice-contiguous image store (critical path) -> flag -> h_allc
        uint2 v0, v1;
        int crow = tid >> 2, j = tid & 3;
        if (tid < 64) {
            v0 = *(const uint2*)(hstg + crow * 32 + j * 8);
            v1 = *(const uint2*)(hstg + crow * 32 + j * 8 + 4);
            char* himg = (char*)hx + ((size_t)((t & 1) * 16 + g) << 14);
            int dstoff = (s << 10) + (crow << 6) + (j << 4);
            asm volatile("global_store_dwordx2 %0, %2, off sc0 sc1\n\t"
                         "global_store_dwordx2 %1, %3, off sc0 sc1"
                         :: "v"(himg + dstoff), "v"(himg + dstoff + 8),
                            "v"(v0), "v"(v1) : "memory");
        }
        asm volatile("s_waitcnt vmcnt(0)" ::: "memory");
        __syncthreads();   // image stores drained before post
        if (tid == 0) {
            int fv = t + 1;
            asm volatile("global_store_dword %0, %1, off sc0 sc1"
                         :: "v"(flags + g * 16 + s), "v"(fv) : "memory");
        }
        if (tid < 64 && crow < nrow) {
            unsigned short* hap = h_allc + (size_t)(pos0 + crow) * NH + s * 32 + j * 8;
            *(uint2*)hap = v0;
            *(uint2*)(hap + 4) = v1;
        }
    }
}

// ---------- final pass: preds = bf2f(logit) - log(rowsum); zeros elsewhere ----
__global__ void norm_k(float* __restrict__ out, const unsigned short* __restrict__ logitb,
                       const float* __restrict__ rowsum,
                       const int* __restrict__ cnt, const int* __restrict__ start) {
    int r = blockIdx.x;          // r = t*256+b, t in [0,31)
    int t = r >> 8, b = r & 255;
    bool act = (t < NT) && (b < cnt[t]);
    float4* row = (float4*)(out + (size_t)b * PRED_B + (size_t)t * NV);
    int tid = threadIdx.x;
    if (act) {
        int pos = start[t] + b;
        float lse = logf(rowsum[pos]);
        const uint4* lrow = (const uint4*)(logitb + (size_t)pos * NV);
        for (int v8 = tid; v8 < NV / 8; v8 += 256) {
            uint4 u = lrow[v8];
            float4 a, c;
            a.x = bf2f((unsigned short)u.x) - lse;
            a.y = bf2f((unsigned short)(u.x >> 16)) - lse;
            a.z = bf2f((unsigned short)u.y) - lse;
            a.w = bf2f((unsigned short)(u.y >> 16)) - lse;
            c.x = bf2f((unsigned short)u.z) - lse;
            c.y = bf2f((unsigned short)(u.z >> 16)) - lse;
            c.z = bf2f((unsigned short)u.w) - lse;
            c.w = bf2f((unsigned short)(u.w >> 16)) - lse;
            row[v8 * 2] = a;
            row[v8 * 2 + 1] = c;
        }
    } else {
        float4 z = make_float4(0.f, 0.f, 0.f, 0.f);
        for (int v4 = tid; v4 < NV / 4; v4 += 256) row[v4] = z;
    }
}

extern "C" void kernel_launch(void* const* d_in, const int* in_sizes, int n_in,
                              void* d_out, int out_size, void* d_ws, size_t ws_size,
                              hipStream_t stream) {
    const float* gimg  = (const float*)d_in[0];
    const int*   w_in  = (const int*)d_in[1];
    const int*   lens  = (const int*)d_in[2];
    const float* emb   = (const float*)d_in[3];
    const float* W_ih  = (const float*)d_in[4];
    const float* W_hh  = (const float*)d_in[5];
    const float* b_ih  = (const float*)d_in[6];
    const float* b_hh  = (const float*)d_in[7];
    const float* W_out = (const float*)d_in[8];
    const float* b_out = (const float*)d_in[9];
    float* out = (float*)d_out;

    char* p = (char*)d_ws;
    auto alloc = [&](size_t bytes) -> char* {
        char* r = p;
        p += (bytes + 255) & ~(size_t)255;
        return r;
    };
    int*   order   = (int*)alloc(NB * 4);
    int*   wsort   = (int*)alloc(NB * ML * 4);
    int*   cnt     = (int*)alloc(NT * 4);
    int*   start   = (int*)alloc((NT + 1) * 4);
    int*   flags   = (int*)alloc(256 * 4);
    int*   rowlist = (int*)alloc((size_t)NT * NB * 4);
    int*   rowwc   = (int*)alloc((size_t)NT * NB * 4);
    float* gx      = (float*)alloc((size_t)NB * NG * 4);
    float* rowsum  = (float*)alloc((size_t)NT * NB * 4);
    unsigned short* g_sb   = (unsigned short*)alloc((size_t)NB * NE * 2);
    unsigned short* hx     = (unsigned short*)alloc((size_t)2 * 16 * 16384);
    unsigned short* h_allc = (unsigned short*)alloc((size_t)NT * NB * NH * 2);
    unsigned short* Wimg2  = (unsigned short*)alloc((size_t)NG * NH * 2);
    unsigned short* Wxl    = (unsigned short*)alloc((size_t)NG * NE * 2);
    unsigned short* Wxb    = (unsigned short*)alloc((size_t)NG * NE * 2);
    unsigned short* Wob    = (unsigned short*)alloc((size_t)NV * NH * 2);
    unsigned short* embb   = (unsigned short*)alloc((size_t)NV * NE * 2);
    unsigned short* gallc  = (unsigned short*)alloc((size_t)NT * NB * NG * 2);
    unsigned short* logitb = (unsigned short*)alloc((size_t)NT * NB * NV * 2);
    int* nact = start + NT;   // n_active lives at start[30]

    sort_k<<<1, 256, 0, stream>>>(lens, order, cnt, start, flags, out + OFF_DEC);
    gather_k<<<NB, 256, 0, stream>>>(gimg, w_in, order, g_sb, wsort, out + OFF_TGT);
    rowlist_k<<<NT, 256, 0, stream>>>(wsort, cnt, start, rowlist, rowwc, rowsum);
    prep_k<<<12560, 256, 0, stream>>>(W_ih, W_hh, W_out, emb, Wxl, Wxb, Wob, embb, Wimg2);

    // gx = g_sb @ Wxl^T + b_ih + b_hh     (256 x 2048, K=512, fp32 out)
    gxgemm<<<dim3(NG / 128, NB / 128), 256, 0, stream>>>(g_sb, Wxl, b_ih, b_hh, gx);

    // gallc[pos][d][q] = bf16( emb[rowwc[pos]] @ Wxb^T + gx[b] )   (n_active x 2048)
    pgemm<1, 0><<<dim3(NT * NB / 128, NG / 128), 256, 0, stream>>>(
        nullptr, rowwc, embb, Wxb, NG, nact, gx, rowlist, gallc, nullptr);

    // fused 30-step recurrence: W-resident, single-writer flag sync (coop)
    {
        void* cargs[] = { (void*)&Wimg2, (void*)&gallc, (void*)&hx, (void*)&h_allc,
                          (void*)&flags, (void*)&cnt, (void*)&start };
        (void)hipLaunchCooperativeKernel((void*)lstmy_k, dim3(256), dim3(256), cargs, 0, stream);
    }

    // logits (bf16 compact) = h_allc @ Wob^T + b_out; rowsum exp-atomics
    pgemm<0, 1><<<dim3(NT * NB / 128, (NV + 127) / 128), 256, 0, stream>>>(
        h_allc, nullptr, nullptr, Wob, NV, nact, b_out, rowlist, logitb, rowsum);

    norm_k<<<(NT + 1) * NB, 256, 0, stream>>>(out, logitb, rowsum, cnt, start);
}